// Round 18
// baseline (538.671 us; speedup 1.0000x reference)
//
#include <hip/hip_runtime.h>
#include <math.h>

#define EPSF 1e-5f

static constexpr int Bn   = 128;   // batch
static constexpr int Tn   = 128;   // conv time steps
static constexpr int Cn   = 32;    // conv in channels
static constexpr int On   = 2048;  // conv out channels = H*Ts
static constexpr int Hn   = 512;
static constexpr int TTn  = 512;   // total SNN steps = T*Ts
static constexpr int HORn = 96;
static constexpr int BH   = Bn * Hn;
static constexpr float THRf = 1.0f;

__device__ __forceinline__ float bf2f(unsigned short u) {
    union { unsigned int i; float f; } v; v.i = ((unsigned int)u) << 16; return v.f;
}
__device__ __forceinline__ unsigned short f2bf(float f) {
    union { float f; unsigned int i; } v; v.f = f;
    unsigned int r = v.i + 0x7fff + ((v.i >> 16) & 1);   // RNE
    return (unsigned short)(r >> 16);
}

using bfrag  = __attribute__((ext_vector_type(8))) short;   // 8 bf16 = 4 VGPRs
using f32x4v = __attribute__((ext_vector_type(4))) float;   // MFMA C/D 16x16
using f32x16 = __attribute__((ext_vector_type(16))) float;  // MFMA C/D 32x32
using us8v   = __attribute__((ext_vector_type(8))) unsigned short;

// Async global->LDS DMA, 16 B per lane; LDS dest = uniform base + lane*16.
#define GLD16(gp, lp) __builtin_amdgcn_global_load_lds( \
    (const __attribute__((address_space(1))) void*)(gp), \
    (__attribute__((address_space(3))) void*)(lp), 16, 0, 0)

// ---------------------------------------------------------------------------
// Merged prep: im2col split-bf16 (idx < NPim), weight repack, sums zeroing.
static constexpr int NPim = Bn * Tn * 96;     // 1572864
static constexpr int NPw  = On * 96;          // 196608
__global__ __launch_bounds__(256) void prep_k(const float* __restrict__ x,
    const float* __restrict__ wconv, unsigned short* __restrict__ Ph,
    unsigned short* __restrict__ Pl, unsigned short* __restrict__ Wh,
    unsigned short* __restrict__ Wl, float* __restrict__ sums)
{
    int idx = blockIdx.x * 256 + threadIdx.x;
    if (idx < 2 * On) sums[idx] = 0.f;        // conv runs after prep; safe
    if (idx < NPim) {
        int row = idx / 96, kc = idx - row * 96;
        int k = kc >> 5, c = kc & 31;
        int t = row & 127, b = row >> 7;
        int tg = t + k - 1;
        float v = (tg >= 0 && tg < Tn) ? x[((size_t)b * Tn + tg) * Cn + c] : 0.f;
        unsigned short hi = f2bf(v);
        Ph[idx] = hi;
        Pl[idx] = f2bf(v - bf2f(hi));
    } else {
        int j = idx - NPim;
        if (j < NPw) {
            int o = j / 96, kc = j - o * 96;
            int k = kc >> 5, c = kc & 31;
            float v = wconv[(size_t)o * 96 + c * 3 + k];
            unsigned short hi = f2bf(v);
            Wh[j] = hi;
            Wl[j] = f2bf(v - bf2f(hi));
        }
    }
}

// Conv as NT MFMA GEMM (split-bf16, hh+hl+lh), fp32 out, fused BN1 stats.
__global__ __launch_bounds__(256) void conv_mfma_k(
    const unsigned short* __restrict__ Ph, const unsigned short* __restrict__ Pl,
    const unsigned short* __restrict__ Wh, const unsigned short* __restrict__ Wl,
    float* __restrict__ raw, float* __restrict__ sums)
{
    const int b  = blockIdx.x;
    const int n0 = blockIdx.y * 128;
    const int tid = threadIdx.x;
    const int lane = tid & 63;
    const int quad = lane >> 4, lr = lane & 15;
    const int wid = tid >> 6, wm = wid & 1, wn = wid >> 1;

    f32x4v acc[4][4] = {};
#pragma unroll
    for (int ks = 0; ks < 3; ks++) {
        const int col = ks * 32 + quad * 8;
        bfrag ah[4], al[4], bh[4], bl[4];
#pragma unroll
        for (int mi = 0; mi < 4; mi++) {
            size_t roff = ((size_t)b * 128 + wm * 64 + mi * 16 + lr) * 96 + col;
            ah[mi] = *(const bfrag*)(Ph + roff);
            al[mi] = *(const bfrag*)(Pl + roff);
        }
#pragma unroll
        for (int ni = 0; ni < 4; ni++) {
            size_t roff = (size_t)(n0 + wn * 64 + ni * 16 + lr) * 96 + col;
            bh[ni] = *(const bfrag*)(Wh + roff);
            bl[ni] = *(const bfrag*)(Wl + roff);
        }
#pragma unroll
        for (int mi = 0; mi < 4; mi++)
#pragma unroll
            for (int ni = 0; ni < 4; ni++) {
                acc[mi][ni] = __builtin_amdgcn_mfma_f32_16x16x32_bf16(
                    ah[mi], bh[ni], acc[mi][ni], 0, 0, 0);
                acc[mi][ni] = __builtin_amdgcn_mfma_f32_16x16x32_bf16(
                    ah[mi], bl[ni], acc[mi][ni], 0, 0, 0);
                acc[mi][ni] = __builtin_amdgcn_mfma_f32_16x16x32_bf16(
                    al[mi], bh[ni], acc[mi][ni], 0, 0, 0);
            }
    }
#pragma unroll
    for (int ni = 0; ni < 4; ni++) {
        int o = n0 + wn * 64 + ni * 16 + lr;
        int ts = o >> 9, hh = o & 511;
        float s = 0.f, ss = 0.f;
#pragma unroll
        for (int mi = 0; mi < 4; mi++)
#pragma unroll
            for (int r = 0; r < 4; r++) {
                int t = wm * 64 + mi * 16 + quad * 4 + r;
                float v = acc[mi][ni][r];
                raw[((size_t)(t * 4 + ts) * Bn + b) * Hn + hh] = v;
                s += v; ss += v * v;
            }
        s  += __shfl_xor(s, 16);  s  += __shfl_xor(s, 32);
        ss += __shfl_xor(ss, 16); ss += __shfl_xor(ss, 32);
        if (quad == 0) {
            atomicAdd(&sums[o], s);
            atomicAdd(&sums[On + o], ss);
        }
    }
}

// ---------------------------------------------------------------------------
// LIF encoder scan, 32 outstanding loads (1 wave/SIMD -> pure ILP cover);
// BN1 finalize inlined from sums.
__global__ __launch_bounds__(256) void lif1_k(const float* __restrict__ raw,
    const float* __restrict__ sums, const float* __restrict__ g,
    const float* __restrict__ bb, const float* __restrict__ beta_in,
    unsigned char* __restrict__ spk)
{
    const int thr = blockIdx.x * 256 + threadIdx.x;
    const int hh = thr & 511;
    const float beta = fminf(fmaxf(beta_in[hh], 0.f), 0.99f);
    float sc[4], sh[4];
#pragma unroll
    for (int ts = 0; ts < 4; ts++) {
        const int o = ts * Hn + hh;
        float m = sums[o] * (1.f / 16384.f);
        float v = sums[On + o] * (1.f / 16384.f) - m * m;
        float scv = g[o] / sqrtf(v + EPSF);
        sc[ts] = scv;
        sh[ts] = bb[o] - m * scv;
    }
    float mem = 0.f;
    for (int tt = 0; tt < TTn; tt += 32) {
        float cu[32];
#pragma unroll
        for (int u = 0; u < 32; u++) cu[u] = raw[(size_t)(tt + u) * BH + thr];
#pragma unroll
        for (int u = 0; u < 32; u++) {
            float cur = cu[u] * sc[u & 3] + sh[u & 3];
            float reset = mem > THRf ? 1.f : 0.f;
            mem = beta * mem + cur - reset;
            spk[(size_t)(tt + u) * BH + thr] = mem > THRf ? (unsigned char)1 : (unsigned char)0;
        }
    }
}

// ---------------------------------------------------------------------------
// Per-step BN over batch, vectorized: uint4 loads, bytewise 32-bit adds.
__global__ __launch_bounds__(256) void bnstep_k(const unsigned char* __restrict__ spk,
    const float* __restrict__ g, const float* __restrict__ bb,
    float* __restrict__ av, float* __restrict__ zv)
{
    const int tt = blockIdx.x;
    const int tid = threadIdx.x;
    const int b0 = tid >> 5;               // 0..7
    const int hseg = (tid & 31) * 16;      // 16 h-bytes per thread
    const unsigned char* base = spk + (size_t)tt * BH;
    uint4 a4 = make_uint4(0u, 0u, 0u, 0u);
#pragma unroll
    for (int i = 0; i < 16; i++) {
        const int b = b0 + i * 8;
        const uint4 v = *(const uint4*)(base + (size_t)b * Hn + hseg);
        a4.x += v.x; a4.y += v.y; a4.z += v.z; a4.w += v.w;
    }
    __shared__ uint4 part[8][32];
    part[b0][tid & 31] = a4;
    __syncthreads();
    if (tid < 32) {
        uint4 s = part[0][tid];
#pragma unroll
        for (int i = 1; i < 8; i++) {
            uint4 p = part[i][tid];
            s.x += p.x; s.y += p.y; s.z += p.z; s.w += p.w;
        }
        unsigned int w[4] = {s.x, s.y, s.z, s.w};
#pragma unroll
        for (int q = 0; q < 16; q++) {
            int cnt = (w[q >> 2] >> ((q & 3) * 8)) & 0xff;
            int hh = tid * 16 + q;
            float p = cnt * (1.f / 128.f);
            float inv = 1.f / sqrtf(p - p * p + EPSF);
            float gi = g[hh] * inv;
            float zz = bb[hh] - p * gi;
            av[(size_t)tt * Hn + hh] = gi + zz;
            zv[(size_t)tt * Hn + hh] = zz;
        }
    }
}

__global__ __launch_bounds__(256) void lif2_k(const unsigned char* __restrict__ sin_,
    const float* __restrict__ av, const float* __restrict__ zv,
    const float* __restrict__ beta_in, unsigned char* __restrict__ sout)
{
    const int thr = blockIdx.x * 256 + threadIdx.x;
    const int hh = thr & 511;
    const float beta = fminf(fmaxf(beta_in[hh], 0.f), 0.99f);
    float mem = 0.f;
    for (int tt = 0; tt < TTn; tt += 32) {
        float aa[32], zz[32]; unsigned char ss[32];
#pragma unroll
        for (int u = 0; u < 32; u++) {
            ss[u] = sin_[(size_t)(tt + u) * BH + thr];
            aa[u] = av[(size_t)(tt + u) * Hn + hh];
            zz[u] = zv[(size_t)(tt + u) * Hn + hh];
        }
#pragma unroll
        for (int u = 0; u < 32; u++) {
            float cur = ss[u] ? aa[u] : zz[u];
            float reset = mem > THRf ? 1.f : 0.f;
            mem = beta * mem + cur - reset;
            sout[(size_t)(tt + u) * BH + thr] = mem > THRf ? (unsigned char)1 : (unsigned char)0;
        }
    }
}

__global__ __launch_bounds__(256) void lif3_k(const unsigned char* __restrict__ sin_,
    const float* __restrict__ av, const float* __restrict__ zv,
    const float* __restrict__ beta_in, unsigned short* __restrict__ mem3b)
{
    const int thr = blockIdx.x * 256 + threadIdx.x;
    const int hh = thr & 511;
    const int b = thr >> 9;
    const float beta = fminf(fmaxf(beta_in[hh], 0.f), 0.99f);
    float mem = 0.f;
    for (int tt = 0; tt < TTn; tt += 32) {
        float aa[32], zz[32]; unsigned char ss[32];
#pragma unroll
        for (int u = 0; u < 32; u++) {
            ss[u] = sin_[(size_t)(tt + u) * BH + thr];
            aa[u] = av[(size_t)(tt + u) * Hn + hh];
            zz[u] = zv[(size_t)(tt + u) * Hn + hh];
        }
#pragma unroll
        for (int u = 0; u < 32; u++) {
            float cur = ss[u] ? aa[u] : zz[u];
            float reset = mem > THRf ? 1.f : 0.f;
            mem = beta * mem + cur - reset;
            mem3b[((size_t)b * TTn + (tt + u)) * Hn + hh] = f2bf(mem);
        }
    }
}

// ---------------------------------------------------------------------------
// Split-K partial: GTp[kz][e][d] = sum_{i in 64-slice kz} wk[i,e] * wq[i,d]
__global__ __launch_bounds__(256) void gemm_atb_k(const float* __restrict__ Aw,
    const float* __restrict__ Bw, float* __restrict__ GTp)
{
    __shared__ float As[8][132];
    __shared__ float Bs[8][132];
    const int m0 = blockIdx.x * 128;
    const int n0 = blockIdx.y * 128;
    const int kz = blockIdx.z;
    const int tid = threadIdx.x;
    const int ir = tid >> 5, cl = (tid & 31) * 4;
    const float* Ap = Aw + (size_t)ir * 512 + m0 + cl;
    const float* Bp = Bw + (size_t)ir * 512 + n0 + cl;
    const int tm = tid & 15, tn = tid >> 4;
    float acc[8][8];
#pragma unroll
    for (int i = 0; i < 8; i++)
#pragma unroll
        for (int j = 0; j < 8; j++) acc[i][j] = 0.f;

    for (int i0 = kz * 64; i0 < kz * 64 + 64; i0 += 8) {
        const float4 avv = *(const float4*)(Ap + (size_t)i0 * 512);
        const float4 bvv = *(const float4*)(Bp + (size_t)i0 * 512);
        __syncthreads();
        *(float4*)&As[ir][cl] = avv;
        *(float4*)&Bs[ir][cl] = bvv;
        __syncthreads();
#pragma unroll
        for (int kk = 0; kk < 8; kk++) {
            float4 a0 = *(const float4*)&As[kk][tm * 8];
            float4 a1 = *(const float4*)&As[kk][tm * 8 + 4];
            float4 b0 = *(const float4*)&Bs[kk][tn * 8];
            float4 b1 = *(const float4*)&Bs[kk][tn * 8 + 4];
            float a_[8] = {a0.x, a0.y, a0.z, a0.w, a1.x, a1.y, a1.z, a1.w};
            float b_[8] = {b0.x, b0.y, b0.z, b0.w, b1.x, b1.y, b1.z, b1.w};
#pragma unroll
            for (int i = 0; i < 8; i++)
#pragma unroll
                for (int j = 0; j < 8; j++) acc[i][j] += a_[i] * b_[j];
        }
    }
    float* outp = GTp + (size_t)kz * Hn * Hn;
#pragma unroll
    for (int i = 0; i < 8; i++) {
        size_t rowoff = (size_t)(m0 + tm * 8 + i) * 512 + n0 + tn * 8;
#pragma unroll
        for (int j = 0; j < 8; j++) outp[rowoff + j] = acc[i][j];
    }
}

// Reduce 8 K-slices -> bf16 GT.
__global__ void gtred_k(const float* __restrict__ GTp, unsigned short* __restrict__ GT)
{
    int idx = blockIdx.x * 256 + threadIdx.x;   // 262144
    float s = 0.f;
#pragma unroll
    for (int z = 0; z < 8; z++) s += GTp[(size_t)z * Hn * Hn + idx];
    GT[idx] = f2bf(s);
}

// blocks 0..15: qb/kb GEMV halves; block 16: c0 = bq.bk
__global__ __launch_bounds__(256) void bias_prep_k(const float* __restrict__ wq,
    const float* __restrict__ wk, const float* __restrict__ bq,
    const float* __restrict__ bk, float* __restrict__ qb, float* __restrict__ kb,
    float* __restrict__ c0)
{
    const int blk = blockIdx.x;
    if (blk == 16) {
        __shared__ float red[256];
        float p = 0.f;
        for (int i = threadIdx.x; i < 512; i += 256) p += bq[i] * bk[i];
        red[threadIdx.x] = p;
        __syncthreads();
        for (int s = 128; s > 0; s >>= 1) {
            if (threadIdx.x < s) red[threadIdx.x] += red[threadIdx.x + s];
            __syncthreads();
        }
        if (threadIdx.x == 0) c0[0] = red[0];
        return;
    }
    const bool doq = blk < 8;
    const int d0 = (doq ? blk : blk - 8) * 64;
    const float* W    = doq ? wq : wk;
    const float* bvec = doq ? bk : bq;
    const int dl = threadIdx.x & 63, ig = threadIdx.x >> 6;
    float s = 0.f;
    for (int i = ig * 128; i < ig * 128 + 128; i++)
        s += W[(size_t)i * 512 + d0 + dl] * bvec[i];
    __shared__ float red2[4][64];
    red2[ig][dl] = s;
    __syncthreads();
    if (ig == 0)
        (doq ? qb : kb)[d0 + dl] = red2[0][dl] + red2[1][dl] + red2[2][dl] + red2[3][dl];
}

// ---------------------------------------------------------------------------
// m97-style MFMA NT GEMM, BK=64, 32x32x16 core, 2-D grid (r13 best config):
// Y[r,e] = sum_d mem3b[r,d] * GT[e,d].  Fused rowq/rowk on blockIdx.y==0.
__global__ __launch_bounds__(256) void ygemm_k(const unsigned short* __restrict__ A,
    const unsigned short* __restrict__ Bsrc, const float* __restrict__ qb,
    const float* __restrict__ kb, const float* __restrict__ c0,
    unsigned short* __restrict__ C, float* __restrict__ rowq,
    float* __restrict__ rowk)
{
    __shared__ unsigned short As[128 * 64];   // 16 KB
    __shared__ unsigned short Bs[128 * 64];
    const int m0 = blockIdx.x * 128;
    const int n0 = blockIdx.y * 128;
    const int tid = threadIdx.x;
    const int lane = tid & 63;
    const int l31 = lane & 31, kw = lane >> 5;
    const int wid = tid >> 6;
    const int wm = wid & 1, wn = wid >> 1;

    const int srw = lane >> 3;
    const int scc = (lane & 7) ^ (srw & 7);
    const unsigned short* gA = A    + (size_t)(m0 + wid * 32 + srw) * 512 + scc * 8;
    const unsigned short* gB = Bsrc + (size_t)(n0 + wid * 32 + srw) * 512 + scc * 8;

    const bool dorows = (blockIdx.y == 0) && (wn == 0);
    float rq_acc[2] = {0.f, 0.f};
    float rk_acc[2] = {0.f, 0.f};

    f32x16 acc[2][2] = {};
    for (int k0 = 0; k0 < 512; k0 += 64) {
        __syncthreads();
#pragma unroll
        for (int j = 0; j < 4; j++) {
            GLD16(gA + (size_t)j * 8 * 512 + k0, As + (wid * 32 + j * 8) * 64);
            GLD16(gB + (size_t)j * 8 * 512 + k0, Bs + (wid * 32 + j * 8) * 64);
        }
        __syncthreads();
#pragma unroll
        for (int kk = 0; kk < 4; kk++) {           // ksteps of 16
            const int chunk = kk * 2 + kw;
            bfrag af[2], bf_[2];
#pragma unroll
            for (int mi = 0; mi < 2; mi++) {
                const int row = wm * 64 + mi * 32 + l31;
                af[mi] = *(const bfrag*)&As[row * 64 + (chunk ^ (row & 7)) * 8];
            }
#pragma unroll
            for (int ni = 0; ni < 2; ni++) {
                const int row = wn * 64 + ni * 32 + l31;
                bf_[ni] = *(const bfrag*)&Bs[row * 64 + (chunk ^ (row & 7)) * 8];
            }
#pragma unroll
            for (int mi = 0; mi < 2; mi++)
#pragma unroll
                for (int ni = 0; ni < 2; ni++)
                    acc[mi][ni] = __builtin_amdgcn_mfma_f32_32x32x16_bf16(
                        af[mi], bf_[ni], acc[mi][ni], 0, 0, 0);
            if (dorows) {
                const int koff = k0 + kk * 16 + kw * 8;
                const float4 qv0 = *(const float4*)(qb + koff);
                const float4 qv1 = *(const float4*)(qb + koff + 4);
                const float4 kv0 = *(const float4*)(kb + koff);
                const float4 kv1 = *(const float4*)(kb + koff + 4);
                const float qv[8] = {qv0.x, qv0.y, qv0.z, qv0.w, qv1.x, qv1.y, qv1.z, qv1.w};
                const float kv[8] = {kv0.x, kv0.y, kv0.z, kv0.w, kv1.x, kv1.y, kv1.z, kv1.w};
#pragma unroll
                for (int mi = 0; mi < 2; mi++)
#pragma unroll
                    for (int j = 0; j < 8; j++) {
                        float a = bf2f((unsigned short)af[mi][j]);
                        rq_acc[mi] += a * qv[j];
                        rk_acc[mi] += a * kv[j];
                    }
            }
        }
    }
#pragma unroll
    for (int mi = 0; mi < 2; mi++)
#pragma unroll
        for (int ni = 0; ni < 2; ni++) {
            const int col = n0 + wn * 64 + ni * 32 + l31;
#pragma unroll
            for (int reg = 0; reg < 16; reg++) {
                const int row = m0 + wm * 64 + mi * 32
                              + (reg & 3) + 8 * (reg >> 2) + 4 * kw;
                C[(size_t)row * 512 + col] = f2bf(acc[mi][ni][reg]);
            }
        }
    if (dorows) {
        const float c0v = c0[0];
#pragma unroll
        for (int mi = 0; mi < 2; mi++) {
            float rq = rq_acc[mi], rk = rk_acc[mi];
            rq += __shfl_xor(rq, 32);
            rk += __shfl_xor(rk, 32);
            if (kw == 0) {
                const int row = m0 + wm * 64 + mi * 32 + l31;
                rowq[row] = rq + c0v;
                rowk[row] = rk;
            }
        }
    }
}

// m97-style MFMA scores, BK=64, 16x16x32 core, 2-D grid; atomic-free output:
// waccp[m_tile][b][s] = this block's colsum * (1/512).
__global__ __launch_bounds__(256) void scores_k(const unsigned short* __restrict__ Y,
    const unsigned short* __restrict__ Xm, const float* __restrict__ rowq,
    const float* __restrict__ rowk, float* __restrict__ waccp)
{
    __shared__ unsigned short As[128 * 64];   // 16 KB
    __shared__ unsigned short Bs[128 * 64];
    __shared__ float colsum[128];
    __shared__ float rq_s[128], rk_s[128];
    const int b  = blockIdx.z;
    const int m0 = blockIdx.x * 128;   // t tile
    const int n0 = blockIdx.y * 128;   // s tile
    const int tid = threadIdx.x;
    const int lane = tid & 63;
    const int quad = lane >> 4, lr = lane & 15;
    const int wid = tid >> 6;
    const int wm = wid & 1, wn = wid >> 1;

    if (tid < 128) {
        colsum[tid] = 0.f;
        rq_s[tid] = rowq[(size_t)b * TTn + m0 + tid];
        rk_s[tid] = rowk[(size_t)b * TTn + n0 + tid];
    }

    const int srw = lane >> 3;                       // row-within-8
    const int scc = (lane & 7) ^ (srw & 7);          // global chunk
    const unsigned short* gA = Y  + (size_t)b * TTn * Hn
        + (size_t)(m0 + wid * 32 + srw) * 512 + scc * 8;
    const unsigned short* gB = Xm + (size_t)b * TTn * Hn
        + (size_t)(n0 + wid * 32 + srw) * 512 + scc * 8;

    f32x4v acc[4][4] = {};
    for (int k0 = 0; k0 < 512; k0 += 64) {
        __syncthreads();
#pragma unroll
        for (int j = 0; j < 4; j++) {
            GLD16(gA + (size_t)j * 8 * 512 + k0, As + (wid * 32 + j * 8) * 64);
            GLD16(gB + (size_t)j * 8 * 512 + k0, Bs + (wid * 32 + j * 8) * 64);
        }
        __syncthreads();
#pragma unroll
        for (int kk = 0; kk < 2; kk++) {
            const int slot = (kk * 4 + quad) ^ (lr & 7);
            bfrag af[4], bf_[4];
#pragma unroll
            for (int mi = 0; mi < 4; mi++)
                af[mi] = *(const bfrag*)&As[(wm * 64 + mi * 16 + lr) * 64 + slot * 8];
#pragma unroll
            for (int ni = 0; ni < 4; ni++)
                bf_[ni] = *(const bfrag*)&Bs[(wn * 64 + ni * 16 + lr) * 64 + slot * 8];
#pragma unroll
            for (int mi = 0; mi < 4; mi++)
#pragma unroll
                for (int ni = 0; ni < 4; ni++)
                    acc[mi][ni] = __builtin_amdgcn_mfma_f32_16x16x32_bf16(
                        af[mi], bf_[ni], acc[mi][ni], 0, 0, 0);
        }
    }
    const float scl = 0.044194173824159216f;
#pragma unroll
    for (int ni = 0; ni < 4; ni++) {
        float s_ln = 0.f;
        float rkv = rk_s[wn * 64 + ni * 16 + lr];
#pragma unroll
        for (int mi = 0; mi < 4; mi++) {
#pragma unroll
            for (int r = 0; r < 4; r++) {
                float rqv = rq_s[wm * 64 + mi * 16 + quad * 4 + r];
                float xv = (acc[mi][ni][r] + rqv + rkv) * scl;
                s_ln += 1.f / (1.f + __expf(-xv));
            }
        }
        atomicAdd(&colsum[wn * 64 + ni * 16 + lr], s_ln);
    }
    __syncthreads();
    if (tid < 128)
        waccp[(((size_t)blockIdx.x * Bn + b) * TTn) + n0 + tid] =
            colsum[tid] * (1.f / 512.f);
}

// Fused wsum+feat: u[b,:] built in LDS from 4 waccp slices, then
// feat[b,d] = u[b,:].wv[d,:] + bv[d]*W1[b].
__global__ __launch_bounds__(256) void wsumfeat_k(const float* __restrict__ waccp,
    const unsigned short* __restrict__ mem3b, const float* __restrict__ wv,
    const float* __restrict__ bv, float* __restrict__ feat)
{
    const int b = blockIdx.x;
    const int tid = threadIdx.x;
    const int wid = tid >> 6, lane = tid & 63;
    __shared__ float ws_[512];
    __shared__ float part[4][512];
    __shared__ float red[256];
    __shared__ float us[512];
    __shared__ float W1s;
#pragma unroll
    for (int h = 0; h < 2; h++) {
        const int s = tid + h * 256;
        float w = 0.f;
#pragma unroll
        for (int z = 0; z < 4; z++)
            w += waccp[(((size_t)z * Bn + b) * TTn) + s];
        ws_[s] = w;
    }
    __syncthreads();
    float a[8] = {0.f, 0.f, 0.f, 0.f, 0.f, 0.f, 0.f, 0.f};
    const unsigned short* Xb = mem3b + (size_t)b * TTn * Hn + lane * 8;
    for (int s = wid * 128; s < wid * 128 + 128; s++) {
        const float w = ws_[s];
        const us8v xv = *(const us8v*)(Xb + (size_t)s * Hn);
#pragma unroll
        for (int j = 0; j < 8; j++) a[j] += w * bf2f(xv[j]);
    }
#pragma unroll
    for (int j = 0; j < 8; j++) part[wid][lane * 8 + j] = a[j];
    red[tid] = ws_[tid] + ws_[tid + 256];
    __syncthreads();
    for (int st = 128; st > 0; st >>= 1) {
        if (tid < st) red[tid] += red[tid + st];
        __syncthreads();
    }
    if (tid == 0) W1s = red[0];
    if (wid == 0) {
#pragma unroll
        for (int j = 0; j < 8; j++) {
            const int e = lane * 8 + j;
            us[e] = part[0][e] + part[1][e] + part[2][e] + part[3][e];
        }
    }
    __syncthreads();
    const float w1 = W1s;
#pragma unroll
    for (int q = 0; q < 2; q++) {
        int d = tid + q * 256;
        float acc = bv[d] * w1;
        const float* wr = wv + (size_t)d * 512;
        for (int e = 0; e < 512; e += 4) {
            float4 w4 = *(const float4*)(wr + e);
            acc += us[e] * w4.x + us[e+1] * w4.y + us[e+2] * w4.z + us[e+3] * w4.w;
        }
        feat[(size_t)b * Hn + d] = acc;
    }
}

// Parallel BN over batch: 8 blocks x 64 d; 4-way b-split + LDS reduce.
__global__ __launch_bounds__(256) void bna_k(const float* __restrict__ feat,
    const float* __restrict__ g, const float* __restrict__ bb,
    float* __restrict__ featn)
{
    const int d0 = blockIdx.x * 64;
    const int dl = threadIdx.x & 63, bg = threadIdx.x >> 6;
    float s = 0.f, ss = 0.f;
    for (int b = bg * 32; b < bg * 32 + 32; b++) {
        float v = feat[(size_t)b * Hn + d0 + dl];
        s += v; ss += v * v;
    }
    __shared__ float ls[4][64], lss[4][64];
    __shared__ float sc_s[64], sh_s[64];
    ls[bg][dl] = s; lss[bg][dl] = ss;
    __syncthreads();
    if (threadIdx.x < 64) {
        float st  = ls[0][dl] + ls[1][dl] + ls[2][dl] + ls[3][dl];
        float sst = lss[0][dl] + lss[1][dl] + lss[2][dl] + lss[3][dl];
        float m = st * (1.f / 128.f);
        float var = sst * (1.f / 128.f) - m * m;
        float sc = g[d0 + dl] / sqrtf(var + EPSF);
        sc_s[dl] = sc;
        sh_s[dl] = bb[d0 + dl] - m * sc;
    }
    __syncthreads();
    for (int b = bg * 32; b < bg * 32 + 32; b++)
        featn[(size_t)b * Hn + d0 + dl] =
            feat[(size_t)b * Hn + d0 + dl] * sc_s[dl] + sh_s[dl];
}

__global__ __launch_bounds__(128) void head_k(const float* __restrict__ featn,
    const float* __restrict__ wh, const float* __restrict__ bh, float* __restrict__ out)
{
    const int b = blockIdx.x;
    __shared__ float f[512];
    const int tid = threadIdx.x;
    for (int i = tid; i < 512; i += 128) f[i] = featn[(size_t)b * Hn + i];
    __syncthreads();
    if (tid < HORn) {
        float accv = bh[tid];
        const float* wr = wh + (size_t)tid * Hn;
        for (int d = 0; d < 512; d++) accv += f[d] * wr[d];
        out[(size_t)b * HORn + tid] = accv;
    }
}

__global__ void dbg_k(float* out, float v) { out[0] = v; }

// ---------------------------------------------------------------------------
extern "C" void kernel_launch(void* const* d_in, const int* in_sizes, int n_in,
                              void* d_out, int out_size, void* d_ws, size_t ws_size,
                              hipStream_t stream)
{
    (void)in_sizes; (void)n_in;
    const float* x      = (const float*)d_in[0];
    const float* conv_w = (const float*)d_in[1];
    const float* bn1_g  = (const float*)d_in[3];
    const float* bn1_b  = (const float*)d_in[4];
    const float* beta_e = (const float*)d_in[5];
    const float* bn2_g  = (const float*)d_in[6];
    const float* bn2_b  = (const float*)d_in[7];
    const float* beta2  = (const float*)d_in[8];
    const float* bn3_g  = (const float*)d_in[9];
    const float* bn3_b  = (const float*)d_in[10];
    const float* beta3  = (const float*)d_in[11];
    const float* wq     = (const float*)d_in[12];
    const float* bq     = (const float*)d_in[13];
    const float* wk     = (const float*)d_in[14];
    const float* bk     = (const float*)d_in[15];
    const float* wv     = (const float*)d_in[16];
    const float* bv     = (const float*)d_in[17];
    const float* bna_g  = (const float*)d_in[18];
    const float* bna_b  = (const float*)d_in[19];
    const float* wh     = (const float*)d_in[20];
    const float* bh     = (const float*)d_in[21];
    float* out = (float*)d_out;

    char* ws = (char*)d_ws;
    size_t off = 0;
    auto alloc = [&](size_t bytes) {
        char* p = ws + off;
        off += (bytes + 255) & ~(size_t)255;
        return p;
    };
    // Region 1: fp32 raw (tt,b,h) 134 MB; aliased by bf16 mem3 (b,tt,h) after lif1.
    float* raw          = (float*)alloc((size_t)TTn * BH * 4);
    // Region 2: spk1 + s2 (67 MB); aliased by bf16 Y (67 MB) after lif3.
    unsigned char* spk1 = (unsigned char*)alloc((size_t)TTn * BH);
    unsigned char* s2   = (unsigned char*)alloc((size_t)TTn * BH);
    unsigned short* Ph = (unsigned short*)alloc((size_t)NPim * 2);
    unsigned short* Pl = (unsigned short*)alloc((size_t)NPim * 2);
    unsigned short* Wh = (unsigned short*)alloc((size_t)NPw * 2);
    unsigned short* Wl = (unsigned short*)alloc((size_t)NPw * 2);
    float* sums   = (float*)alloc(2 * On * 4);
    float* a2     = (float*)alloc((size_t)TTn * Hn * 4);
    float* z2     = (float*)alloc((size_t)TTn * Hn * 4);
    float* a3     = (float*)alloc((size_t)TTn * Hn * 4);
    float* z3     = (float*)alloc((size_t)TTn * Hn * 4);
    float* waccp  = (float*)alloc((size_t)4 * Bn * TTn * 4);   // per-m-tile slices
    float* GTp    = (float*)alloc((size_t)8 * Hn * Hn * 4);    // split-K partials
    unsigned short* GT = (unsigned short*)alloc((size_t)Hn * Hn * 2);
    float* qb     = (float*)alloc(Hn * 4);
    float* kb     = (float*)alloc(Hn * 4);
    float* c0     = (float*)alloc(256);
    float* rowq   = (float*)alloc((size_t)Bn * TTn * 4);
    float* rowk   = (float*)alloc((size_t)Bn * TTn * 4);
    float* feat   = (float*)alloc((size_t)Bn * Hn * 4);
    float* featn  = (float*)alloc((size_t)Bn * Hn * 4);
    unsigned short* mem3b = (unsigned short*)raw;   // raw dead after lif1
    unsigned short* Y     = (unsigned short*)spk1;  // spikes dead after lif3

    if (ws_size < off) {
        hipMemsetAsync(d_out, 0, (size_t)out_size * 4, stream);
        dbg_k<<<1, 1, 0, stream>>>(out, (float)ws_size);
        return;
    }

    prep_k<<<(NPim + NPw + 255) / 256, 256, 0, stream>>>(x, conv_w, Ph, Pl, Wh, Wl, sums);
    conv_mfma_k<<<dim3(Bn, On / 128), 256, 0, stream>>>(Ph, Pl, Wh, Wl, raw, sums);
    lif1_k<<<BH / 256, 256, 0, stream>>>(raw, sums, bn1_g, bn1_b, beta_e, spk1);
    bnstep_k<<<TTn, 256, 0, stream>>>(spk1, bn2_g, bn2_b, a2, z2);
    lif2_k<<<BH / 256, 256, 0, stream>>>(spk1, a2, z2, beta2, s2);
    bnstep_k<<<TTn, 256, 0, stream>>>(s2, bn3_g, bn3_b, a3, z3);
    lif3_k<<<BH / 256, 256, 0, stream>>>(s2, a3, z3, beta3, mem3b);
    gemm_atb_k<<<dim3(4, 4, 8), 256, 0, stream>>>(wk, wq, GTp);  // split-K partials
    gtred_k<<<(Hn * Hn) / 256, 256, 0, stream>>>(GTp, GT);       // GT = G^T (bf16)
    bias_prep_k<<<17, 256, 0, stream>>>(wq, wk, bq, bk, qb, kb, c0);
    ygemm_k<<<dim3((Bn * TTn) / 128, Hn / 128), 256, 0, stream>>>(
        mem3b, GT, qb, kb, c0, Y, rowq, rowk);
    scores_k<<<dim3(TTn / 128, TTn / 128, Bn), 256, 0, stream>>>(
        Y, mem3b, rowq, rowk, waccp);
    wsumfeat_k<<<Bn, 256, 0, stream>>>(waccp, mem3b, wv, bv, feat);
    bna_k<<<Hn / 64, 256, 0, stream>>>(feat, bna_g, bna_b, featn);
    head_k<<<Bn, 128, 0, stream>>>(featn, wh, bh, out);
}

// Round 19
// 521.236 us; speedup vs baseline: 1.0334x; 1.0334x over previous
//
#include <hip/hip_runtime.h>
#include <math.h>

#define EPSF 1e-5f

static constexpr int Bn   = 128;   // batch
static constexpr int Tn   = 128;   // conv time steps
static constexpr int Cn   = 32;    // conv in channels
static constexpr int On   = 2048;  // conv out channels = H*Ts
static constexpr int Hn   = 512;
static constexpr int TTn  = 512;   // total SNN steps = T*Ts
static constexpr int HORn = 96;
static constexpr int BH   = Bn * Hn;
static constexpr float THRf = 1.0f;

__device__ __forceinline__ float bf2f(unsigned short u) {
    union { unsigned int i; float f; } v; v.i = ((unsigned int)u) << 16; return v.f;
}
__device__ __forceinline__ unsigned short f2bf(float f) {
    union { float f; unsigned int i; } v; v.f = f;
    unsigned int r = v.i + 0x7fff + ((v.i >> 16) & 1);   // RNE
    return (unsigned short)(r >> 16);
}

using bfrag  = __attribute__((ext_vector_type(8))) short;   // 8 bf16 = 4 VGPRs
using f32x4v = __attribute__((ext_vector_type(4))) float;   // MFMA C/D 16x16
using f32x16 = __attribute__((ext_vector_type(16))) float;  // MFMA C/D 32x32
using us8v   = __attribute__((ext_vector_type(8))) unsigned short;

// Async global->LDS DMA, 16 B per lane; LDS dest = uniform base + lane*16.
#define GLD16(gp, lp) __builtin_amdgcn_global_load_lds( \
    (const __attribute__((address_space(1))) void*)(gp), \
    (__attribute__((address_space(3))) void*)(lp), 16, 0, 0)

// ---------------------------------------------------------------------------
// Merged prep: im2col split-bf16 (idx < NPim), weight repack, sums zeroing.
static constexpr int NPim = Bn * Tn * 96;     // 1572864
static constexpr int NPw  = On * 96;          // 196608
__global__ __launch_bounds__(256) void prep_k(const float* __restrict__ x,
    const float* __restrict__ wconv, unsigned short* __restrict__ Ph,
    unsigned short* __restrict__ Pl, unsigned short* __restrict__ Wh,
    unsigned short* __restrict__ Wl, float* __restrict__ sums)
{
    int idx = blockIdx.x * 256 + threadIdx.x;
    if (idx < 2 * On) sums[idx] = 0.f;        // conv runs after prep; safe
    if (idx < NPim) {
        int row = idx / 96, kc = idx - row * 96;
        int k = kc >> 5, c = kc & 31;
        int t = row & 127, b = row >> 7;
        int tg = t + k - 1;
        float v = (tg >= 0 && tg < Tn) ? x[((size_t)b * Tn + tg) * Cn + c] : 0.f;
        unsigned short hi = f2bf(v);
        Ph[idx] = hi;
        Pl[idx] = f2bf(v - bf2f(hi));
    } else {
        int j = idx - NPim;
        if (j < NPw) {
            int o = j / 96, kc = j - o * 96;
            int k = kc >> 5, c = kc & 31;
            float v = wconv[(size_t)o * 96 + c * 3 + k];
            unsigned short hi = f2bf(v);
            Wh[j] = hi;
            Wl[j] = f2bf(v - bf2f(hi));
        }
    }
}

// Conv as NT MFMA GEMM (split-bf16, hh+hl+lh), fp32 out, fused BN1 stats.
__global__ __launch_bounds__(256) void conv_mfma_k(
    const unsigned short* __restrict__ Ph, const unsigned short* __restrict__ Pl,
    const unsigned short* __restrict__ Wh, const unsigned short* __restrict__ Wl,
    float* __restrict__ raw, float* __restrict__ sums)
{
    const int b  = blockIdx.x;
    const int n0 = blockIdx.y * 128;
    const int tid = threadIdx.x;
    const int lane = tid & 63;
    const int quad = lane >> 4, lr = lane & 15;
    const int wid = tid >> 6, wm = wid & 1, wn = wid >> 1;

    f32x4v acc[4][4] = {};
#pragma unroll
    for (int ks = 0; ks < 3; ks++) {
        const int col = ks * 32 + quad * 8;
        bfrag ah[4], al[4], bh[4], bl[4];
#pragma unroll
        for (int mi = 0; mi < 4; mi++) {
            size_t roff = ((size_t)b * 128 + wm * 64 + mi * 16 + lr) * 96 + col;
            ah[mi] = *(const bfrag*)(Ph + roff);
            al[mi] = *(const bfrag*)(Pl + roff);
        }
#pragma unroll
        for (int ni = 0; ni < 4; ni++) {
            size_t roff = (size_t)(n0 + wn * 64 + ni * 16 + lr) * 96 + col;
            bh[ni] = *(const bfrag*)(Wh + roff);
            bl[ni] = *(const bfrag*)(Wl + roff);
        }
#pragma unroll
        for (int mi = 0; mi < 4; mi++)
#pragma unroll
            for (int ni = 0; ni < 4; ni++) {
                acc[mi][ni] = __builtin_amdgcn_mfma_f32_16x16x32_bf16(
                    ah[mi], bh[ni], acc[mi][ni], 0, 0, 0);
                acc[mi][ni] = __builtin_amdgcn_mfma_f32_16x16x32_bf16(
                    ah[mi], bl[ni], acc[mi][ni], 0, 0, 0);
                acc[mi][ni] = __builtin_amdgcn_mfma_f32_16x16x32_bf16(
                    al[mi], bh[ni], acc[mi][ni], 0, 0, 0);
            }
    }
#pragma unroll
    for (int ni = 0; ni < 4; ni++) {
        int o = n0 + wn * 64 + ni * 16 + lr;
        int ts = o >> 9, hh = o & 511;
        float s = 0.f, ss = 0.f;
#pragma unroll
        for (int mi = 0; mi < 4; mi++)
#pragma unroll
            for (int r = 0; r < 4; r++) {
                int t = wm * 64 + mi * 16 + quad * 4 + r;
                float v = acc[mi][ni][r];
                raw[((size_t)(t * 4 + ts) * Bn + b) * Hn + hh] = v;
                s += v; ss += v * v;
            }
        s  += __shfl_xor(s, 16);  s  += __shfl_xor(s, 32);
        ss += __shfl_xor(ss, 16); ss += __shfl_xor(ss, 32);
        if (quad == 0) {
            atomicAdd(&sums[o], s);
            atomicAdd(&sums[On + o], ss);
        }
    }
}

// ---------------------------------------------------------------------------
// LIF encoder scan, 32 outstanding loads (fits vmcnt<=63);
// __launch_bounds__(256,1): grid is 1 wave/SIMD so free the VGPR budget.
__global__ __launch_bounds__(256, 1) void lif1_k(const float* __restrict__ raw,
    const float* __restrict__ sums, const float* __restrict__ g,
    const float* __restrict__ bb, const float* __restrict__ beta_in,
    unsigned char* __restrict__ spk)
{
    const int thr = blockIdx.x * 256 + threadIdx.x;
    const int hh = thr & 511;
    const float beta = fminf(fmaxf(beta_in[hh], 0.f), 0.99f);
    float sc[4], sh[4];
#pragma unroll
    for (int ts = 0; ts < 4; ts++) {
        const int o = ts * Hn + hh;
        float m = sums[o] * (1.f / 16384.f);
        float v = sums[On + o] * (1.f / 16384.f) - m * m;
        float scv = g[o] / sqrtf(v + EPSF);
        sc[ts] = scv;
        sh[ts] = bb[o] - m * scv;
    }
    float mem = 0.f;
    for (int tt = 0; tt < TTn; tt += 32) {
        float cu[32];
#pragma unroll
        for (int u = 0; u < 32; u++) cu[u] = raw[(size_t)(tt + u) * BH + thr];
#pragma unroll
        for (int u = 0; u < 32; u++) {
            float cur = cu[u] * sc[u & 3] + sh[u & 3];
            float reset = mem > THRf ? 1.f : 0.f;
            mem = beta * mem + cur - reset;
            spk[(size_t)(tt + u) * BH + thr] = mem > THRf ? (unsigned char)1 : (unsigned char)0;
        }
    }
}

// ---------------------------------------------------------------------------
// Per-step BN over batch, vectorized; writes interleaved {a,z} float2.
__global__ __launch_bounds__(256) void bnstep_k(const unsigned char* __restrict__ spk,
    const float* __restrict__ g, const float* __restrict__ bb,
    float2* __restrict__ azv)
{
    const int tt = blockIdx.x;
    const int tid = threadIdx.x;
    const int b0 = tid >> 5;               // 0..7
    const int hseg = (tid & 31) * 16;      // 16 h-bytes per thread
    const unsigned char* base = spk + (size_t)tt * BH;
    uint4 a4 = make_uint4(0u, 0u, 0u, 0u);
#pragma unroll
    for (int i = 0; i < 16; i++) {
        const int b = b0 + i * 8;
        const uint4 v = *(const uint4*)(base + (size_t)b * Hn + hseg);
        a4.x += v.x; a4.y += v.y; a4.z += v.z; a4.w += v.w;
    }
    __shared__ uint4 part[8][32];
    part[b0][tid & 31] = a4;
    __syncthreads();
    if (tid < 32) {
        uint4 s = part[0][tid];
#pragma unroll
        for (int i = 1; i < 8; i++) {
            uint4 p = part[i][tid];
            s.x += p.x; s.y += p.y; s.z += p.z; s.w += p.w;
        }
        unsigned int w[4] = {s.x, s.y, s.z, s.w};
#pragma unroll
        for (int q = 0; q < 16; q++) {
            int cnt = (w[q >> 2] >> ((q & 3) * 8)) & 0xff;
            int hh = tid * 16 + q;
            float p = cnt * (1.f / 128.f);
            float inv = 1.f / sqrtf(p - p * p + EPSF);
            float gi = g[hh] * inv;
            float zz = bb[hh] - p * gi;
            azv[(size_t)tt * Hn + hh] = make_float2(gi + zz, zz);
        }
    }
}

// LIF scan over spikes: 16-deep (16 ss + 16 az = 32 outstanding <= vmcnt cap),
// interleaved float2 {a,z} loads.
__global__ __launch_bounds__(256, 1) void lif2_k(const unsigned char* __restrict__ sin_,
    const float2* __restrict__ azv, const float* __restrict__ beta_in,
    unsigned char* __restrict__ sout)
{
    const int thr = blockIdx.x * 256 + threadIdx.x;
    const int hh = thr & 511;
    const float beta = fminf(fmaxf(beta_in[hh], 0.f), 0.99f);
    float mem = 0.f;
    for (int tt = 0; tt < TTn; tt += 16) {
        float2 az[16]; unsigned char ss[16];
#pragma unroll
        for (int u = 0; u < 16; u++) {
            ss[u] = sin_[(size_t)(tt + u) * BH + thr];
            az[u] = azv[(size_t)(tt + u) * Hn + hh];
        }
#pragma unroll
        for (int u = 0; u < 16; u++) {
            float cur = ss[u] ? az[u].x : az[u].y;
            float reset = mem > THRf ? 1.f : 0.f;
            mem = beta * mem + cur - reset;
            sout[(size_t)(tt + u) * BH + thr] = mem > THRf ? (unsigned char)1 : (unsigned char)0;
        }
    }
}

__global__ __launch_bounds__(256, 1) void lif3_k(const unsigned char* __restrict__ sin_,
    const float2* __restrict__ azv, const float* __restrict__ beta_in,
    unsigned short* __restrict__ mem3b)
{
    const int thr = blockIdx.x * 256 + threadIdx.x;
    const int hh = thr & 511;
    const int b = thr >> 9;
    const float beta = fminf(fmaxf(beta_in[hh], 0.f), 0.99f);
    float mem = 0.f;
    for (int tt = 0; tt < TTn; tt += 16) {
        float2 az[16]; unsigned char ss[16];
#pragma unroll
        for (int u = 0; u < 16; u++) {
            ss[u] = sin_[(size_t)(tt + u) * BH + thr];
            az[u] = azv[(size_t)(tt + u) * Hn + hh];
        }
#pragma unroll
        for (int u = 0; u < 16; u++) {
            float cur = ss[u] ? az[u].x : az[u].y;
            float reset = mem > THRf ? 1.f : 0.f;
            mem = beta * mem + cur - reset;
            mem3b[((size_t)b * TTn + (tt + u)) * Hn + hh] = f2bf(mem);
        }
    }
}

// ---------------------------------------------------------------------------
// Split-K partial: GTp[kz][e][d] = sum_{i in 64-slice kz} wk[i,e] * wq[i,d]
__global__ __launch_bounds__(256) void gemm_atb_k(const float* __restrict__ Aw,
    const float* __restrict__ Bw, float* __restrict__ GTp)
{
    __shared__ float As[8][132];
    __shared__ float Bs[8][132];
    const int m0 = blockIdx.x * 128;
    const int n0 = blockIdx.y * 128;
    const int kz = blockIdx.z;
    const int tid = threadIdx.x;
    const int ir = tid >> 5, cl = (tid & 31) * 4;
    const float* Ap = Aw + (size_t)ir * 512 + m0 + cl;
    const float* Bp = Bw + (size_t)ir * 512 + n0 + cl;
    const int tm = tid & 15, tn = tid >> 4;
    float acc[8][8];
#pragma unroll
    for (int i = 0; i < 8; i++)
#pragma unroll
        for (int j = 0; j < 8; j++) acc[i][j] = 0.f;

    for (int i0 = kz * 64; i0 < kz * 64 + 64; i0 += 8) {
        const float4 avv = *(const float4*)(Ap + (size_t)i0 * 512);
        const float4 bvv = *(const float4*)(Bp + (size_t)i0 * 512);
        __syncthreads();
        *(float4*)&As[ir][cl] = avv;
        *(float4*)&Bs[ir][cl] = bvv;
        __syncthreads();
#pragma unroll
        for (int kk = 0; kk < 8; kk++) {
            float4 a0 = *(const float4*)&As[kk][tm * 8];
            float4 a1 = *(const float4*)&As[kk][tm * 8 + 4];
            float4 b0 = *(const float4*)&Bs[kk][tn * 8];
            float4 b1 = *(const float4*)&Bs[kk][tn * 8 + 4];
            float a_[8] = {a0.x, a0.y, a0.z, a0.w, a1.x, a1.y, a1.z, a1.w};
            float b_[8] = {b0.x, b0.y, b0.z, b0.w, b1.x, b1.y, b1.z, b1.w};
#pragma unroll
            for (int i = 0; i < 8; i++)
#pragma unroll
                for (int j = 0; j < 8; j++) acc[i][j] += a_[i] * b_[j];
        }
    }
    float* outp = GTp + (size_t)kz * Hn * Hn;
#pragma unroll
    for (int i = 0; i < 8; i++) {
        size_t rowoff = (size_t)(m0 + tm * 8 + i) * 512 + n0 + tn * 8;
#pragma unroll
        for (int j = 0; j < 8; j++) outp[rowoff + j] = acc[i][j];
    }
}

// Reduce 8 K-slices -> bf16 GT.
__global__ void gtred_k(const float* __restrict__ GTp, unsigned short* __restrict__ GT)
{
    int idx = blockIdx.x * 256 + threadIdx.x;   // 262144
    float s = 0.f;
#pragma unroll
    for (int z = 0; z < 8; z++) s += GTp[(size_t)z * Hn * Hn + idx];
    GT[idx] = f2bf(s);
}

// blocks 0..15: qb/kb GEMV halves; block 16: c0 = bq.bk
__global__ __launch_bounds__(256) void bias_prep_k(const float* __restrict__ wq,
    const float* __restrict__ wk, const float* __restrict__ bq,
    const float* __restrict__ bk, float* __restrict__ qb, float* __restrict__ kb,
    float* __restrict__ c0)
{
    const int blk = blockIdx.x;
    if (blk == 16) {
        __shared__ float red[256];
        float p = 0.f;
        for (int i = threadIdx.x; i < 512; i += 256) p += bq[i] * bk[i];
        red[threadIdx.x] = p;
        __syncthreads();
        for (int s = 128; s > 0; s >>= 1) {
            if (threadIdx.x < s) red[threadIdx.x] += red[threadIdx.x + s];
            __syncthreads();
        }
        if (threadIdx.x == 0) c0[0] = red[0];
        return;
    }
    const bool doq = blk < 8;
    const int d0 = (doq ? blk : blk - 8) * 64;
    const float* W    = doq ? wq : wk;
    const float* bvec = doq ? bk : bq;
    const int dl = threadIdx.x & 63, ig = threadIdx.x >> 6;
    float s = 0.f;
    for (int i = ig * 128; i < ig * 128 + 128; i++)
        s += W[(size_t)i * 512 + d0 + dl] * bvec[i];
    __shared__ float red2[4][64];
    red2[ig][dl] = s;
    __syncthreads();
    if (ig == 0)
        (doq ? qb : kb)[d0 + dl] = red2[0][dl] + red2[1][dl] + red2[2][dl] + red2[3][dl];
}

// ---------------------------------------------------------------------------
// m97-style MFMA NT GEMM, BK=64, 32x32x16 core, 2-D grid (r13 best config):
// Y[r,e] = sum_d mem3b[r,d] * GT[e,d].  Fused rowq/rowk on blockIdx.y==0.
__global__ __launch_bounds__(256) void ygemm_k(const unsigned short* __restrict__ A,
    const unsigned short* __restrict__ Bsrc, const float* __restrict__ qb,
    const float* __restrict__ kb, const float* __restrict__ c0,
    unsigned short* __restrict__ C, float* __restrict__ rowq,
    float* __restrict__ rowk)
{
    __shared__ unsigned short As[128 * 64];   // 16 KB
    __shared__ unsigned short Bs[128 * 64];
    const int m0 = blockIdx.x * 128;
    const int n0 = blockIdx.y * 128;
    const int tid = threadIdx.x;
    const int lane = tid & 63;
    const int l31 = lane & 31, kw = lane >> 5;
    const int wid = tid >> 6;
    const int wm = wid & 1, wn = wid >> 1;

    const int srw = lane >> 3;
    const int scc = (lane & 7) ^ (srw & 7);
    const unsigned short* gA = A    + (size_t)(m0 + wid * 32 + srw) * 512 + scc * 8;
    const unsigned short* gB = Bsrc + (size_t)(n0 + wid * 32 + srw) * 512 + scc * 8;

    const bool dorows = (blockIdx.y == 0) && (wn == 0);
    float rq_acc[2] = {0.f, 0.f};
    float rk_acc[2] = {0.f, 0.f};

    f32x16 acc[2][2] = {};
    for (int k0 = 0; k0 < 512; k0 += 64) {
        __syncthreads();
#pragma unroll
        for (int j = 0; j < 4; j++) {
            GLD16(gA + (size_t)j * 8 * 512 + k0, As + (wid * 32 + j * 8) * 64);
            GLD16(gB + (size_t)j * 8 * 512 + k0, Bs + (wid * 32 + j * 8) * 64);
        }
        __syncthreads();
#pragma unroll
        for (int kk = 0; kk < 4; kk++) {           // ksteps of 16
            const int chunk = kk * 2 + kw;
            bfrag af[2], bf_[2];
#pragma unroll
            for (int mi = 0; mi < 2; mi++) {
                const int row = wm * 64 + mi * 32 + l31;
                af[mi] = *(const bfrag*)&As[row * 64 + (chunk ^ (row & 7)) * 8];
            }
#pragma unroll
            for (int ni = 0; ni < 2; ni++) {
                const int row = wn * 64 + ni * 32 + l31;
                bf_[ni] = *(const bfrag*)&Bs[row * 64 + (chunk ^ (row & 7)) * 8];
            }
#pragma unroll
            for (int mi = 0; mi < 2; mi++)
#pragma unroll
                for (int ni = 0; ni < 2; ni++)
                    acc[mi][ni] = __builtin_amdgcn_mfma_f32_32x32x16_bf16(
                        af[mi], bf_[ni], acc[mi][ni], 0, 0, 0);
            if (dorows) {
                const int koff = k0 + kk * 16 + kw * 8;
                const float4 qv0 = *(const float4*)(qb + koff);
                const float4 qv1 = *(const float4*)(qb + koff + 4);
                const float4 kv0 = *(const float4*)(kb + koff);
                const float4 kv1 = *(const float4*)(kb + koff + 4);
                const float qv[8] = {qv0.x, qv0.y, qv0.z, qv0.w, qv1.x, qv1.y, qv1.z, qv1.w};
                const float kv[8] = {kv0.x, kv0.y, kv0.z, kv0.w, kv1.x, kv1.y, kv1.z, kv1.w};
#pragma unroll
                for (int mi = 0; mi < 2; mi++)
#pragma unroll
                    for (int j = 0; j < 8; j++) {
                        float a = bf2f((unsigned short)af[mi][j]);
                        rq_acc[mi] += a * qv[j];
                        rk_acc[mi] += a * kv[j];
                    }
            }
        }
    }
#pragma unroll
    for (int mi = 0; mi < 2; mi++)
#pragma unroll
        for (int ni = 0; ni < 2; ni++) {
            const int col = n0 + wn * 64 + ni * 32 + l31;
#pragma unroll
            for (int reg = 0; reg < 16; reg++) {
                const int row = m0 + wm * 64 + mi * 32
                              + (reg & 3) + 8 * (reg >> 2) + 4 * kw;
                C[(size_t)row * 512 + col] = f2bf(acc[mi][ni][reg]);
            }
        }
    if (dorows) {
        const float c0v = c0[0];
#pragma unroll
        for (int mi = 0; mi < 2; mi++) {
            float rq = rq_acc[mi], rk = rk_acc[mi];
            rq += __shfl_xor(rq, 32);
            rk += __shfl_xor(rk, 32);
            if (kw == 0) {
                const int row = m0 + wm * 64 + mi * 32 + l31;
                rowq[row] = rq + c0v;
                rowk[row] = rk;
            }
        }
    }
}

// m97-style MFMA scores, BK=64, 16x16x32 core, 2-D grid; atomic-free output:
// waccp[m_tile][b][s] = this block's colsum * (1/512).
__global__ __launch_bounds__(256) void scores_k(const unsigned short* __restrict__ Y,
    const unsigned short* __restrict__ Xm, const float* __restrict__ rowq,
    const float* __restrict__ rowk, float* __restrict__ waccp)
{
    __shared__ unsigned short As[128 * 64];   // 16 KB
    __shared__ unsigned short Bs[128 * 64];
    __shared__ float colsum[128];
    __shared__ float rq_s[128], rk_s[128];
    const int b  = blockIdx.z;
    const int m0 = blockIdx.x * 128;   // t tile
    const int n0 = blockIdx.y * 128;   // s tile
    const int tid = threadIdx.x;
    const int lane = tid & 63;
    const int quad = lane >> 4, lr = lane & 15;
    const int wid = tid >> 6;
    const int wm = wid & 1, wn = wid >> 1;

    if (tid < 128) {
        colsum[tid] = 0.f;
        rq_s[tid] = rowq[(size_t)b * TTn + m0 + tid];
        rk_s[tid] = rowk[(size_t)b * TTn + n0 + tid];
    }

    const int srw = lane >> 3;                       // row-within-8
    const int scc = (lane & 7) ^ (srw & 7);          // global chunk
    const unsigned short* gA = Y  + (size_t)b * TTn * Hn
        + (size_t)(m0 + wid * 32 + srw) * 512 + scc * 8;
    const unsigned short* gB = Xm + (size_t)b * TTn * Hn
        + (size_t)(n0 + wid * 32 + srw) * 512 + scc * 8;

    f32x4v acc[4][4] = {};
    for (int k0 = 0; k0 < 512; k0 += 64) {
        __syncthreads();
#pragma unroll
        for (int j = 0; j < 4; j++) {
            GLD16(gA + (size_t)j * 8 * 512 + k0, As + (wid * 32 + j * 8) * 64);
            GLD16(gB + (size_t)j * 8 * 512 + k0, Bs + (wid * 32 + j * 8) * 64);
        }
        __syncthreads();
#pragma unroll
        for (int kk = 0; kk < 2; kk++) {
            const int slot = (kk * 4 + quad) ^ (lr & 7);
            bfrag af[4], bf_[4];
#pragma unroll
            for (int mi = 0; mi < 4; mi++)
                af[mi] = *(const bfrag*)&As[(wm * 64 + mi * 16 + lr) * 64 + slot * 8];
#pragma unroll
            for (int ni = 0; ni < 4; ni++)
                bf_[ni] = *(const bfrag*)&Bs[(wn * 64 + ni * 16 + lr) * 64 + slot * 8];
#pragma unroll
            for (int mi = 0; mi < 4; mi++)
#pragma unroll
                for (int ni = 0; ni < 4; ni++)
                    acc[mi][ni] = __builtin_amdgcn_mfma_f32_16x16x32_bf16(
                        af[mi], bf_[ni], acc[mi][ni], 0, 0, 0);
        }
    }
    const float scl = 0.044194173824159216f;
#pragma unroll
    for (int ni = 0; ni < 4; ni++) {
        float s_ln = 0.f;
        float rkv = rk_s[wn * 64 + ni * 16 + lr];
#pragma unroll
        for (int mi = 0; mi < 4; mi++) {
#pragma unroll
            for (int r = 0; r < 4; r++) {
                float rqv = rq_s[wm * 64 + mi * 16 + quad * 4 + r];
                float xv = (acc[mi][ni][r] + rqv + rkv) * scl;
                s_ln += 1.f / (1.f + __expf(-xv));
            }
        }
        atomicAdd(&colsum[wn * 64 + ni * 16 + lr], s_ln);
    }
    __syncthreads();
    if (tid < 128)
        waccp[(((size_t)blockIdx.x * Bn + b) * TTn) + n0 + tid] =
            colsum[tid] * (1.f / 512.f);
}

// Fused wsum+feat: u[b,:] built in LDS from 4 waccp slices, then
// feat[b,d] = u[b,:].wv[d,:] + bv[d]*W1[b].
__global__ __launch_bounds__(256) void wsumfeat_k(const float* __restrict__ waccp,
    const unsigned short* __restrict__ mem3b, const float* __restrict__ wv,
    const float* __restrict__ bv, float* __restrict__ feat)
{
    const int b = blockIdx.x;
    const int tid = threadIdx.x;
    const int wid = tid >> 6, lane = tid & 63;
    __shared__ float ws_[512];
    __shared__ float part[4][512];
    __shared__ float red[256];
    __shared__ float us[512];
    __shared__ float W1s;
#pragma unroll
    for (int h = 0; h < 2; h++) {
        const int s = tid + h * 256;
        float w = 0.f;
#pragma unroll
        for (int z = 0; z < 4; z++)
            w += waccp[(((size_t)z * Bn + b) * TTn) + s];
        ws_[s] = w;
    }
    __syncthreads();
    float a[8] = {0.f, 0.f, 0.f, 0.f, 0.f, 0.f, 0.f, 0.f};
    const unsigned short* Xb = mem3b + (size_t)b * TTn * Hn + lane * 8;
    for (int s = wid * 128; s < wid * 128 + 128; s++) {
        const float w = ws_[s];
        const us8v xv = *(const us8v*)(Xb + (size_t)s * Hn);
#pragma unroll
        for (int j = 0; j < 8; j++) a[j] += w * bf2f(xv[j]);
    }
#pragma unroll
    for (int j = 0; j < 8; j++) part[wid][lane * 8 + j] = a[j];
    red[tid] = ws_[tid] + ws_[tid + 256];
    __syncthreads();
    for (int st = 128; st > 0; st >>= 1) {
        if (tid < st) red[tid] += red[tid + st];
        __syncthreads();
    }
    if (tid == 0) W1s = red[0];
    if (wid == 0) {
#pragma unroll
        for (int j = 0; j < 8; j++) {
            const int e = lane * 8 + j;
            us[e] = part[0][e] + part[1][e] + part[2][e] + part[3][e];
        }
    }
    __syncthreads();
    const float w1 = W1s;
#pragma unroll
    for (int q = 0; q < 2; q++) {
        int d = tid + q * 256;
        float acc = bv[d] * w1;
        const float* wr = wv + (size_t)d * 512;
        for (int e = 0; e < 512; e += 4) {
            float4 w4 = *(const float4*)(wr + e);
            acc += us[e] * w4.x + us[e+1] * w4.y + us[e+2] * w4.z + us[e+3] * w4.w;
        }
        feat[(size_t)b * Hn + d] = acc;
    }
}

// Parallel BN over batch: 8 blocks x 64 d; 4-way b-split + LDS reduce.
__global__ __launch_bounds__(256) void bna_k(const float* __restrict__ feat,
    const float* __restrict__ g, const float* __restrict__ bb,
    float* __restrict__ featn)
{
    const int d0 = blockIdx.x * 64;
    const int dl = threadIdx.x & 63, bg = threadIdx.x >> 6;
    float s = 0.f, ss = 0.f;
    for (int b = bg * 32; b < bg * 32 + 32; b++) {
        float v = feat[(size_t)b * Hn + d0 + dl];
        s += v; ss += v * v;
    }
    __shared__ float ls[4][64], lss[4][64];
    __shared__ float sc_s[64], sh_s[64];
    ls[bg][dl] = s; lss[bg][dl] = ss;
    __syncthreads();
    if (threadIdx.x < 64) {
        float st  = ls[0][dl] + ls[1][dl] + ls[2][dl] + ls[3][dl];
        float sst = lss[0][dl] + lss[1][dl] + lss[2][dl] + lss[3][dl];
        float m = st * (1.f / 128.f);
        float var = sst * (1.f / 128.f) - m * m;
        float sc = g[d0 + dl] / sqrtf(var + EPSF);
        sc_s[dl] = sc;
        sh_s[dl] = bb[d0 + dl] - m * sc;
    }
    __syncthreads();
    for (int b = bg * 32; b < bg * 32 + 32; b++)
        featn[(size_t)b * Hn + d0 + dl] =
            feat[(size_t)b * Hn + d0 + dl] * sc_s[dl] + sh_s[dl];
}

__global__ __launch_bounds__(128) void head_k(const float* __restrict__ featn,
    const float* __restrict__ wh, const float* __restrict__ bh, float* __restrict__ out)
{
    const int b = blockIdx.x;
    __shared__ float f[512];
    const int tid = threadIdx.x;
    for (int i = tid; i < 512; i += 128) f[i] = featn[(size_t)b * Hn + i];
    __syncthreads();
    if (tid < HORn) {
        float accv = bh[tid];
        const float* wr = wh + (size_t)tid * Hn;
        for (int d = 0; d < 512; d++) accv += f[d] * wr[d];
        out[(size_t)b * HORn + tid] = accv;
    }
}

__global__ void dbg_k(float* out, float v) { out[0] = v; }

// ---------------------------------------------------------------------------
extern "C" void kernel_launch(void* const* d_in, const int* in_sizes, int n_in,
                              void* d_out, int out_size, void* d_ws, size_t ws_size,
                              hipStream_t stream)
{
    (void)in_sizes; (void)n_in;
    const float* x      = (const float*)d_in[0];
    const float* conv_w = (const float*)d_in[1];
    const float* bn1_g  = (const float*)d_in[3];
    const float* bn1_b  = (const float*)d_in[4];
    const float* beta_e = (const float*)d_in[5];
    const float* bn2_g  = (const float*)d_in[6];
    const float* bn2_b  = (const float*)d_in[7];
    const float* beta2  = (const float*)d_in[8];
    const float* bn3_g  = (const float*)d_in[9];
    const float* bn3_b  = (const float*)d_in[10];
    const float* beta3  = (const float*)d_in[11];
    const float* wq     = (const float*)d_in[12];
    const float* bq     = (const float*)d_in[13];
    const float* wk     = (const float*)d_in[14];
    const float* bk     = (const float*)d_in[15];
    const float* wv     = (const float*)d_in[16];
    const float* bv     = (const float*)d_in[17];
    const float* bna_g  = (const float*)d_in[18];
    const float* bna_b  = (const float*)d_in[19];
    const float* wh     = (const float*)d_in[20];
    const float* bh     = (const float*)d_in[21];
    float* out = (float*)d_out;

    char* ws = (char*)d_ws;
    size_t off = 0;
    auto alloc = [&](size_t bytes) {
        char* p = ws + off;
        off += (bytes + 255) & ~(size_t)255;
        return p;
    };
    // Region 1: fp32 raw (tt,b,h) 134 MB; aliased by bf16 mem3 (b,tt,h) after lif1.
    float* raw          = (float*)alloc((size_t)TTn * BH * 4);
    // Region 2: spk1 + s2 (67 MB); aliased by bf16 Y (67 MB) after lif3.
    unsigned char* spk1 = (unsigned char*)alloc((size_t)TTn * BH);
    unsigned char* s2   = (unsigned char*)alloc((size_t)TTn * BH);
    unsigned short* Ph = (unsigned short*)alloc((size_t)NPim * 2);
    unsigned short* Pl = (unsigned short*)alloc((size_t)NPim * 2);
    unsigned short* Wh = (unsigned short*)alloc((size_t)NPw * 2);
    unsigned short* Wl = (unsigned short*)alloc((size_t)NPw * 2);
    float* sums   = (float*)alloc(2 * On * 4);
    float2* az2   = (float2*)alloc((size_t)TTn * Hn * 8);
    float2* az3   = (float2*)alloc((size_t)TTn * Hn * 8);
    float* waccp  = (float*)alloc((size_t)4 * Bn * TTn * 4);   // per-m-tile slices
    float* GTp    = (float*)alloc((size_t)8 * Hn * Hn * 4);    // split-K partials
    unsigned short* GT = (unsigned short*)alloc((size_t)Hn * Hn * 2);
    float* qb     = (float*)alloc(Hn * 4);
    float* kb     = (float*)alloc(Hn * 4);
    float* c0     = (float*)alloc(256);
    float* rowq   = (float*)alloc((size_t)Bn * TTn * 4);
    float* rowk   = (float*)alloc((size_t)Bn * TTn * 4);
    float* feat   = (float*)alloc((size_t)Bn * Hn * 4);
    float* featn  = (float*)alloc((size_t)Bn * Hn * 4);
    unsigned short* mem3b = (unsigned short*)raw;   // raw dead after lif1
    unsigned short* Y     = (unsigned short*)spk1;  // spikes dead after lif3

    if (ws_size < off) {
        hipMemsetAsync(d_out, 0, (size_t)out_size * 4, stream);
        dbg_k<<<1, 1, 0, stream>>>(out, (float)ws_size);
        return;
    }

    prep_k<<<(NPim + NPw + 255) / 256, 256, 0, stream>>>(x, conv_w, Ph, Pl, Wh, Wl, sums);
    conv_mfma_k<<<dim3(Bn, On / 128), 256, 0, stream>>>(Ph, Pl, Wh, Wl, raw, sums);
    lif1_k<<<BH / 256, 256, 0, stream>>>(raw, sums, bn1_g, bn1_b, beta_e, spk1);
    bnstep_k<<<TTn, 256, 0, stream>>>(spk1, bn2_g, bn2_b, az2);
    lif2_k<<<BH / 256, 256, 0, stream>>>(spk1, az2, beta2, s2);
    bnstep_k<<<TTn, 256, 0, stream>>>(s2, bn3_g, bn3_b, az3);
    lif3_k<<<BH / 256, 256, 0, stream>>>(s2, az3, beta3, mem3b);
    gemm_atb_k<<<dim3(4, 4, 8), 256, 0, stream>>>(wk, wq, GTp);  // split-K partials
    gtred_k<<<(Hn * Hn) / 256, 256, 0, stream>>>(GTp, GT);       // GT = G^T (bf16)
    bias_prep_k<<<17, 256, 0, stream>>>(wq, wk, bq, bk, qb, kb, c0);
    ygemm_k<<<dim3((Bn * TTn) / 128, Hn / 128), 256, 0, stream>>>(
        mem3b, GT, qb, kb, c0, Y, rowq, rowk);
    scores_k<<<dim3(TTn / 128, TTn / 128, Bn), 256, 0, stream>>>(
        Y, mem3b, rowq, rowk, waccp);
    wsumfeat_k<<<Bn, 256, 0, stream>>>(waccp, mem3b, wv, bv, feat);
    bna_k<<<Hn / 64, 256, 0, stream>>>(feat, bna_g, bna_b, featn);
    head_k<<<Bn, 128, 0, stream>>>(featn, wh, bh, out);
}

// Round 20
// 472.954 us; speedup vs baseline: 1.1389x; 1.1021x over previous
//
#include <hip/hip_runtime.h>
#include <math.h>

#define EPSF 1e-5f

static constexpr int Bn   = 128;   // batch
static constexpr int Tn   = 128;   // conv time steps
static constexpr int Cn   = 32;    // conv in channels
static constexpr int On   = 2048;  // conv out channels = H*Ts
static constexpr int Hn   = 512;
static constexpr int TTn  = 512;   // total SNN steps = T*Ts
static constexpr int HORn = 96;
static constexpr int BH   = Bn * Hn;
static constexpr float THRf = 1.0f;

__device__ __forceinline__ float bf2f(unsigned short u) {
    union { unsigned int i; float f; } v; v.i = ((unsigned int)u) << 16; return v.f;
}
__device__ __forceinline__ unsigned short f2bf(float f) {
    union { float f; unsigned int i; } v; v.f = f;
    unsigned int r = v.i + 0x7fff + ((v.i >> 16) & 1);   // RNE
    return (unsigned short)(r >> 16);
}

using bfrag  = __attribute__((ext_vector_type(8))) short;   // 8 bf16 = 4 VGPRs
using f32x4v = __attribute__((ext_vector_type(4))) float;   // MFMA C/D 16x16
using f32x16 = __attribute__((ext_vector_type(16))) float;  // MFMA C/D 32x32
using us8v   = __attribute__((ext_vector_type(8))) unsigned short;

// Async global->LDS DMA, 16 B per lane; LDS dest = uniform base + lane*16.
#define GLD16(gp, lp) __builtin_amdgcn_global_load_lds( \
    (const __attribute__((address_space(1))) void*)(gp), \
    (__attribute__((address_space(3))) void*)(lp), 16, 0, 0)

// ---------------------------------------------------------------------------
// Merged prep: im2col split-bf16 (idx < NPim), weight repack, sums zeroing.
static constexpr int NPim = Bn * Tn * 96;     // 1572864
static constexpr int NPw  = On * 96;          // 196608
__global__ __launch_bounds__(256) void prep_k(const float* __restrict__ x,
    const float* __restrict__ wconv, unsigned short* __restrict__ Ph,
    unsigned short* __restrict__ Pl, unsigned short* __restrict__ Wh,
    unsigned short* __restrict__ Wl, float* __restrict__ sums)
{
    int idx = blockIdx.x * 256 + threadIdx.x;
    if (idx < 2 * On) sums[idx] = 0.f;        // conv runs after prep; safe
    if (idx < NPim) {
        int row = idx / 96, kc = idx - row * 96;
        int k = kc >> 5, c = kc & 31;
        int t = row & 127, b = row >> 7;
        int tg = t + k - 1;
        float v = (tg >= 0 && tg < Tn) ? x[((size_t)b * Tn + tg) * Cn + c] : 0.f;
        unsigned short hi = f2bf(v);
        Ph[idx] = hi;
        Pl[idx] = f2bf(v - bf2f(hi));
    } else {
        int j = idx - NPim;
        if (j < NPw) {
            int o = j / 96, kc = j - o * 96;
            int k = kc >> 5, c = kc & 31;
            float v = wconv[(size_t)o * 96 + c * 3 + k];
            unsigned short hi = f2bf(v);
            Wh[j] = hi;
            Wl[j] = f2bf(v - bf2f(hi));
        }
    }
}

// Conv as NT MFMA GEMM (split-bf16, hh+hl+lh), fp32 out, fused BN1 stats.
__global__ __launch_bounds__(256) void conv_mfma_k(
    const unsigned short* __restrict__ Ph, const unsigned short* __restrict__ Pl,
    const unsigned short* __restrict__ Wh, const unsigned short* __restrict__ Wl,
    float* __restrict__ raw, float* __restrict__ sums)
{
    const int b  = blockIdx.x;
    const int n0 = blockIdx.y * 128;
    const int tid = threadIdx.x;
    const int lane = tid & 63;
    const int quad = lane >> 4, lr = lane & 15;
    const int wid = tid >> 6, wm = wid & 1, wn = wid >> 1;

    f32x4v acc[4][4] = {};
#pragma unroll
    for (int ks = 0; ks < 3; ks++) {
        const int col = ks * 32 + quad * 8;
        bfrag ah[4], al[4], bh[4], bl[4];
#pragma unroll
        for (int mi = 0; mi < 4; mi++) {
            size_t roff = ((size_t)b * 128 + wm * 64 + mi * 16 + lr) * 96 + col;
            ah[mi] = *(const bfrag*)(Ph + roff);
            al[mi] = *(const bfrag*)(Pl + roff);
        }
#pragma unroll
        for (int ni = 0; ni < 4; ni++) {
            size_t roff = (size_t)(n0 + wn * 64 + ni * 16 + lr) * 96 + col;
            bh[ni] = *(const bfrag*)(Wh + roff);
            bl[ni] = *(const bfrag*)(Wl + roff);
        }
#pragma unroll
        for (int mi = 0; mi < 4; mi++)
#pragma unroll
            for (int ni = 0; ni < 4; ni++) {
                acc[mi][ni] = __builtin_amdgcn_mfma_f32_16x16x32_bf16(
                    ah[mi], bh[ni], acc[mi][ni], 0, 0, 0);
                acc[mi][ni] = __builtin_amdgcn_mfma_f32_16x16x32_bf16(
                    ah[mi], bl[ni], acc[mi][ni], 0, 0, 0);
                acc[mi][ni] = __builtin_amdgcn_mfma_f32_16x16x32_bf16(
                    al[mi], bh[ni], acc[mi][ni], 0, 0, 0);
            }
    }
#pragma unroll
    for (int ni = 0; ni < 4; ni++) {
        int o = n0 + wn * 64 + ni * 16 + lr;
        int ts = o >> 9, hh = o & 511;
        float s = 0.f, ss = 0.f;
#pragma unroll
        for (int mi = 0; mi < 4; mi++)
#pragma unroll
            for (int r = 0; r < 4; r++) {
                int t = wm * 64 + mi * 16 + quad * 4 + r;
                float v = acc[mi][ni][r];
                raw[((size_t)(t * 4 + ts) * Bn + b) * Hn + hh] = v;
                s += v; ss += v * v;
            }
        s  += __shfl_xor(s, 16);  s  += __shfl_xor(s, 32);
        ss += __shfl_xor(ss, 16); ss += __shfl_xor(ss, 32);
        if (quad == 0) {
            atomicAdd(&sums[o], s);
            atomicAdd(&sums[On + o], ss);
        }
    }
}

// ---------------------------------------------------------------------------
// LIF encoder scan, 16 outstanding loads (r17 best config); BN1 inlined.
__global__ __launch_bounds__(256) void lif1_k(const float* __restrict__ raw,
    const float* __restrict__ sums, const float* __restrict__ g,
    const float* __restrict__ bb, const float* __restrict__ beta_in,
    unsigned char* __restrict__ spk)
{
    const int thr = blockIdx.x * 256 + threadIdx.x;
    const int hh = thr & 511;
    const float beta = fminf(fmaxf(beta_in[hh], 0.f), 0.99f);
    float sc[4], sh[4];
#pragma unroll
    for (int ts = 0; ts < 4; ts++) {
        const int o = ts * Hn + hh;
        float m = sums[o] * (1.f / 16384.f);
        float v = sums[On + o] * (1.f / 16384.f) - m * m;
        float scv = g[o] / sqrtf(v + EPSF);
        sc[ts] = scv;
        sh[ts] = bb[o] - m * scv;
    }
    float mem = 0.f;
    for (int tt = 0; tt < TTn; tt += 16) {
        float cu[16];
#pragma unroll
        for (int u = 0; u < 16; u++) cu[u] = raw[(size_t)(tt + u) * BH + thr];
#pragma unroll
        for (int u = 0; u < 16; u++) {
            float cur = cu[u] * sc[u & 3] + sh[u & 3];
            float reset = mem > THRf ? 1.f : 0.f;
            mem = beta * mem + cur - reset;
            spk[(size_t)(tt + u) * BH + thr] = mem > THRf ? (unsigned char)1 : (unsigned char)0;
        }
    }
}

// ---------------------------------------------------------------------------
// Per-step BN over batch, vectorized: uint4 loads, bytewise 32-bit adds.
__global__ __launch_bounds__(256) void bnstep_k(const unsigned char* __restrict__ spk,
    const float* __restrict__ g, const float* __restrict__ bb,
    float* __restrict__ av, float* __restrict__ zv)
{
    const int tt = blockIdx.x;
    const int tid = threadIdx.x;
    const int b0 = tid >> 5;               // 0..7
    const int hseg = (tid & 31) * 16;      // 16 h-bytes per thread
    const unsigned char* base = spk + (size_t)tt * BH;
    uint4 a4 = make_uint4(0u, 0u, 0u, 0u);
#pragma unroll
    for (int i = 0; i < 16; i++) {
        const int b = b0 + i * 8;
        const uint4 v = *(const uint4*)(base + (size_t)b * Hn + hseg);
        a4.x += v.x; a4.y += v.y; a4.z += v.z; a4.w += v.w;
    }
    __shared__ uint4 part[8][32];
    part[b0][tid & 31] = a4;
    __syncthreads();
    if (tid < 32) {
        uint4 s = part[0][tid];
#pragma unroll
        for (int i = 1; i < 8; i++) {
            uint4 p = part[i][tid];
            s.x += p.x; s.y += p.y; s.z += p.z; s.w += p.w;
        }
        unsigned int w[4] = {s.x, s.y, s.z, s.w};
#pragma unroll
        for (int q = 0; q < 16; q++) {
            int cnt = (w[q >> 2] >> ((q & 3) * 8)) & 0xff;
            int hh = tid * 16 + q;
            float p = cnt * (1.f / 128.f);
            float inv = 1.f / sqrtf(p - p * p + EPSF);
            float gi = g[hh] * inv;
            float zz = bb[hh] - p * gi;
            av[(size_t)tt * Hn + hh] = gi + zz;
            zv[(size_t)tt * Hn + hh] = zz;
        }
    }
}

__global__ __launch_bounds__(256) void lif2_k(const unsigned char* __restrict__ sin_,
    const float* __restrict__ av, const float* __restrict__ zv,
    const float* __restrict__ beta_in, unsigned char* __restrict__ sout)
{
    const int thr = blockIdx.x * 256 + threadIdx.x;
    const int hh = thr & 511;
    const float beta = fminf(fmaxf(beta_in[hh], 0.f), 0.99f);
    float mem = 0.f;
    for (int tt = 0; tt < TTn; tt += 16) {
        float aa[16], zz[16]; unsigned char ss[16];
#pragma unroll
        for (int u = 0; u < 16; u++) {
            ss[u] = sin_[(size_t)(tt + u) * BH + thr];
            aa[u] = av[(size_t)(tt + u) * Hn + hh];
            zz[u] = zv[(size_t)(tt + u) * Hn + hh];
        }
#pragma unroll
        for (int u = 0; u < 16; u++) {
            float cur = ss[u] ? aa[u] : zz[u];
            float reset = mem > THRf ? 1.f : 0.f;
            mem = beta * mem + cur - reset;
            sout[(size_t)(tt + u) * BH + thr] = mem > THRf ? (unsigned char)1 : (unsigned char)0;
        }
    }
}

__global__ __launch_bounds__(256) void lif3_k(const unsigned char* __restrict__ sin_,
    const float* __restrict__ av, const float* __restrict__ zv,
    const float* __restrict__ beta_in, unsigned short* __restrict__ mem3b)
{
    const int thr = blockIdx.x * 256 + threadIdx.x;
    const int hh = thr & 511;
    const int b = thr >> 9;
    const float beta = fminf(fmaxf(beta_in[hh], 0.f), 0.99f);
    float mem = 0.f;
    for (int tt = 0; tt < TTn; tt += 16) {
        float aa[16], zz[16]; unsigned char ss[16];
#pragma unroll
        for (int u = 0; u < 16; u++) {
            ss[u] = sin_[(size_t)(tt + u) * BH + thr];
            aa[u] = av[(size_t)(tt + u) * Hn + hh];
            zz[u] = zv[(size_t)(tt + u) * Hn + hh];
        }
#pragma unroll
        for (int u = 0; u < 16; u++) {
            float cur = ss[u] ? aa[u] : zz[u];
            float reset = mem > THRf ? 1.f : 0.f;
            mem = beta * mem + cur - reset;
            mem3b[((size_t)b * TTn + (tt + u)) * Hn + hh] = f2bf(mem);
        }
    }
}

// ---------------------------------------------------------------------------
// Split-K partial: GTp[kz][e][d] = sum_{i in 64-slice kz} wk[i,e] * wq[i,d]
__global__ __launch_bounds__(256) void gemm_atb_k(const float* __restrict__ Aw,
    const float* __restrict__ Bw, float* __restrict__ GTp)
{
    __shared__ float As[8][132];
    __shared__ float Bs[8][132];
    const int m0 = blockIdx.x * 128;
    const int n0 = blockIdx.y * 128;
    const int kz = blockIdx.z;
    const int tid = threadIdx.x;
    const int ir = tid >> 5, cl = (tid & 31) * 4;
    const float* Ap = Aw + (size_t)ir * 512 + m0 + cl;
    const float* Bp = Bw + (size_t)ir * 512 + n0 + cl;
    const int tm = tid & 15, tn = tid >> 4;
    float acc[8][8];
#pragma unroll
    for (int i = 0; i < 8; i++)
#pragma unroll
        for (int j = 0; j < 8; j++) acc[i][j] = 0.f;

    for (int i0 = kz * 64; i0 < kz * 64 + 64; i0 += 8) {
        const float4 avv = *(const float4*)(Ap + (size_t)i0 * 512);
        const float4 bvv = *(const float4*)(Bp + (size_t)i0 * 512);
        __syncthreads();
        *(float4*)&As[ir][cl] = avv;
        *(float4*)&Bs[ir][cl] = bvv;
        __syncthreads();
#pragma unroll
        for (int kk = 0; kk < 8; kk++) {
            float4 a0 = *(const float4*)&As[kk][tm * 8];
            float4 a1 = *(const float4*)&As[kk][tm * 8 + 4];
            float4 b0 = *(const float4*)&Bs[kk][tn * 8];
            float4 b1 = *(const float4*)&Bs[kk][tn * 8 + 4];
            float a_[8] = {a0.x, a0.y, a0.z, a0.w, a1.x, a1.y, a1.z, a1.w};
            float b_[8] = {b0.x, b0.y, b0.z, b0.w, b1.x, b1.y, b1.z, b1.w};
#pragma unroll
            for (int i = 0; i < 8; i++)
#pragma unroll
                for (int j = 0; j < 8; j++) acc[i][j] += a_[i] * b_[j];
        }
    }
    float* outp = GTp + (size_t)kz * Hn * Hn;
#pragma unroll
    for (int i = 0; i < 8; i++) {
        size_t rowoff = (size_t)(m0 + tm * 8 + i) * 512 + n0 + tn * 8;
#pragma unroll
        for (int j = 0; j < 8; j++) outp[rowoff + j] = acc[i][j];
    }
}

// Reduce 8 K-slices -> bf16 GT.
__global__ void gtred_k(const float* __restrict__ GTp, unsigned short* __restrict__ GT)
{
    int idx = blockIdx.x * 256 + threadIdx.x;   // 262144
    float s = 0.f;
#pragma unroll
    for (int z = 0; z < 8; z++) s += GTp[(size_t)z * Hn * Hn + idx];
    GT[idx] = f2bf(s);
}

// blocks 0..15: qb/kb GEMV halves; block 16: c0 = bq.bk
__global__ __launch_bounds__(256) void bias_prep_k(const float* __restrict__ wq,
    const float* __restrict__ wk, const float* __restrict__ bq,
    const float* __restrict__ bk, float* __restrict__ qb, float* __restrict__ kb,
    float* __restrict__ c0)
{
    const int blk = blockIdx.x;
    if (blk == 16) {
        __shared__ float red[256];
        float p = 0.f;
        for (int i = threadIdx.x; i < 512; i += 256) p += bq[i] * bk[i];
        red[threadIdx.x] = p;
        __syncthreads();
        for (int s = 128; s > 0; s >>= 1) {
            if (threadIdx.x < s) red[threadIdx.x] += red[threadIdx.x + s];
            __syncthreads();
        }
        if (threadIdx.x == 0) c0[0] = red[0];
        return;
    }
    const bool doq = blk < 8;
    const int d0 = (doq ? blk : blk - 8) * 64;
    const float* W    = doq ? wq : wk;
    const float* bvec = doq ? bk : bq;
    const int dl = threadIdx.x & 63, ig = threadIdx.x >> 6;
    float s = 0.f;
    for (int i = ig * 128; i < ig * 128 + 128; i++)
        s += W[(size_t)i * 512 + d0 + dl] * bvec[i];
    __shared__ float red2[4][64];
    red2[ig][dl] = s;
    __syncthreads();
    if (ig == 0)
        (doq ? qb : kb)[d0 + dl] = red2[0][dl] + red2[1][dl] + red2[2][dl] + red2[3][dl];
}

// ---------------------------------------------------------------------------
// m97-style MFMA NT GEMM, BK=64, 32x32x16 core, 2-D grid (r13 best config):
// Y[r,e] = sum_d mem3b[r,d] * GT[e,d].  Fused rowq/rowk on blockIdx.y==0.
__global__ __launch_bounds__(256) void ygemm_k(const unsigned short* __restrict__ A,
    const unsigned short* __restrict__ Bsrc, const float* __restrict__ qb,
    const float* __restrict__ kb, const float* __restrict__ c0,
    unsigned short* __restrict__ C, float* __restrict__ rowq,
    float* __restrict__ rowk)
{
    __shared__ unsigned short As[128 * 64];   // 16 KB
    __shared__ unsigned short Bs[128 * 64];
    const int m0 = blockIdx.x * 128;
    const int n0 = blockIdx.y * 128;
    const int tid = threadIdx.x;
    const int lane = tid & 63;
    const int l31 = lane & 31, kw = lane >> 5;
    const int wid = tid >> 6;
    const int wm = wid & 1, wn = wid >> 1;

    const int srw = lane >> 3;
    const int scc = (lane & 7) ^ (srw & 7);
    const unsigned short* gA = A    + (size_t)(m0 + wid * 32 + srw) * 512 + scc * 8;
    const unsigned short* gB = Bsrc + (size_t)(n0 + wid * 32 + srw) * 512 + scc * 8;

    const bool dorows = (blockIdx.y == 0) && (wn == 0);
    float rq_acc[2] = {0.f, 0.f};
    float rk_acc[2] = {0.f, 0.f};

    f32x16 acc[2][2] = {};
    for (int k0 = 0; k0 < 512; k0 += 64) {
        __syncthreads();
#pragma unroll
        for (int j = 0; j < 4; j++) {
            GLD16(gA + (size_t)j * 8 * 512 + k0, As + (wid * 32 + j * 8) * 64);
            GLD16(gB + (size_t)j * 8 * 512 + k0, Bs + (wid * 32 + j * 8) * 64);
        }
        __syncthreads();
#pragma unroll
        for (int kk = 0; kk < 4; kk++) {           // ksteps of 16
            const int chunk = kk * 2 + kw;
            bfrag af[2], bf_[2];
#pragma unroll
            for (int mi = 0; mi < 2; mi++) {
                const int row = wm * 64 + mi * 32 + l31;
                af[mi] = *(const bfrag*)&As[row * 64 + (chunk ^ (row & 7)) * 8];
            }
#pragma unroll
            for (int ni = 0; ni < 2; ni++) {
                const int row = wn * 64 + ni * 32 + l31;
                bf_[ni] = *(const bfrag*)&Bs[row * 64 + (chunk ^ (row & 7)) * 8];
            }
#pragma unroll
            for (int mi = 0; mi < 2; mi++)
#pragma unroll
                for (int ni = 0; ni < 2; ni++)
                    acc[mi][ni] = __builtin_amdgcn_mfma_f32_32x32x16_bf16(
                        af[mi], bf_[ni], acc[mi][ni], 0, 0, 0);
            if (dorows) {
                const int koff = k0 + kk * 16 + kw * 8;
                const float4 qv0 = *(const float4*)(qb + koff);
                const float4 qv1 = *(const float4*)(qb + koff + 4);
                const float4 kv0 = *(const float4*)(kb + koff);
                const float4 kv1 = *(const float4*)(kb + koff + 4);
                const float qv[8] = {qv0.x, qv0.y, qv0.z, qv0.w, qv1.x, qv1.y, qv1.z, qv1.w};
                const float kv[8] = {kv0.x, kv0.y, kv0.z, kv0.w, kv1.x, kv1.y, kv1.z, kv1.w};
#pragma unroll
                for (int mi = 0; mi < 2; mi++)
#pragma unroll
                    for (int j = 0; j < 8; j++) {
                        float a = bf2f((unsigned short)af[mi][j]);
                        rq_acc[mi] += a * qv[j];
                        rk_acc[mi] += a * kv[j];
                    }
            }
        }
    }
#pragma unroll
    for (int mi = 0; mi < 2; mi++)
#pragma unroll
        for (int ni = 0; ni < 2; ni++) {
            const int col = n0 + wn * 64 + ni * 32 + l31;
#pragma unroll
            for (int reg = 0; reg < 16; reg++) {
                const int row = m0 + wm * 64 + mi * 32
                              + (reg & 3) + 8 * (reg >> 2) + 4 * kw;
                C[(size_t)row * 512 + col] = f2bf(acc[mi][ni][reg]);
            }
        }
    if (dorows) {
        const float c0v = c0[0];
#pragma unroll
        for (int mi = 0; mi < 2; mi++) {
            float rq = rq_acc[mi], rk = rk_acc[mi];
            rq += __shfl_xor(rq, 32);
            rk += __shfl_xor(rk, 32);
            if (kw == 0) {
                const int row = m0 + wm * 64 + mi * 32 + l31;
                rowq[row] = rq + c0v;
                rowk[row] = rk;
            }
        }
    }
}

// m97-style MFMA scores, BK=64, 16x16x32 core, 2-D grid; atomic-free output:
// waccp[m_tile][b][s] = this block's colsum * (1/512).
__global__ __launch_bounds__(256) void scores_k(const unsigned short* __restrict__ Y,
    const unsigned short* __restrict__ Xm, const float* __restrict__ rowq,
    const float* __restrict__ rowk, float* __restrict__ waccp)
{
    __shared__ unsigned short As[128 * 64];   // 16 KB
    __shared__ unsigned short Bs[128 * 64];
    __shared__ float colsum[128];
    __shared__ float rq_s[128], rk_s[128];
    const int b  = blockIdx.z;
    const int m0 = blockIdx.x * 128;   // t tile
    const int n0 = blockIdx.y * 128;   // s tile
    const int tid = threadIdx.x;
    const int lane = tid & 63;
    const int quad = lane >> 4, lr = lane & 15;
    const int wid = tid >> 6;
    const int wm = wid & 1, wn = wid >> 1;

    if (tid < 128) {
        colsum[tid] = 0.f;
        rq_s[tid] = rowq[(size_t)b * TTn + m0 + tid];
        rk_s[tid] = rowk[(size_t)b * TTn + n0 + tid];
    }

    const int srw = lane >> 3;                       // row-within-8
    const int scc = (lane & 7) ^ (srw & 7);          // global chunk
    const unsigned short* gA = Y  + (size_t)b * TTn * Hn
        + (size_t)(m0 + wid * 32 + srw) * 512 + scc * 8;
    const unsigned short* gB = Xm + (size_t)b * TTn * Hn
        + (size_t)(n0 + wid * 32 + srw) * 512 + scc * 8;

    f32x4v acc[4][4] = {};
    for (int k0 = 0; k0 < 512; k0 += 64) {
        __syncthreads();
#pragma unroll
        for (int j = 0; j < 4; j++) {
            GLD16(gA + (size_t)j * 8 * 512 + k0, As + (wid * 32 + j * 8) * 64);
            GLD16(gB + (size_t)j * 8 * 512 + k0, Bs + (wid * 32 + j * 8) * 64);
        }
        __syncthreads();
#pragma unroll
        for (int kk = 0; kk < 2; kk++) {
            const int slot = (kk * 4 + quad) ^ (lr & 7);
            bfrag af[4], bf_[4];
#pragma unroll
            for (int mi = 0; mi < 4; mi++)
                af[mi] = *(const bfrag*)&As[(wm * 64 + mi * 16 + lr) * 64 + slot * 8];
#pragma unroll
            for (int ni = 0; ni < 4; ni++)
                bf_[ni] = *(const bfrag*)&Bs[(wn * 64 + ni * 16 + lr) * 64 + slot * 8];
#pragma unroll
            for (int mi = 0; mi < 4; mi++)
#pragma unroll
                for (int ni = 0; ni < 4; ni++)
                    acc[mi][ni] = __builtin_amdgcn_mfma_f32_16x16x32_bf16(
                        af[mi], bf_[ni], acc[mi][ni], 0, 0, 0);
        }
    }
    const float scl = 0.044194173824159216f;
#pragma unroll
    for (int ni = 0; ni < 4; ni++) {
        float s_ln = 0.f;
        float rkv = rk_s[wn * 64 + ni * 16 + lr];
#pragma unroll
        for (int mi = 0; mi < 4; mi++) {
#pragma unroll
            for (int r = 0; r < 4; r++) {
                float rqv = rq_s[wm * 64 + mi * 16 + quad * 4 + r];
                float xv = (acc[mi][ni][r] + rqv + rkv) * scl;
                s_ln += 1.f / (1.f + __expf(-xv));
            }
        }
        atomicAdd(&colsum[wn * 64 + ni * 16 + lr], s_ln);
    }
    __syncthreads();
    if (tid < 128)
        waccp[(((size_t)blockIdx.x * Bn + b) * TTn) + n0 + tid] =
            colsum[tid] * (1.f / 512.f);
}

// Fused wsum+feat: u[b,:] built in LDS from 4 waccp slices, then
// feat[b,d] = u[b,:].wv[d,:] + bv[d]*W1[b].
__global__ __launch_bounds__(256) void wsumfeat_k(const float* __restrict__ waccp,
    const unsigned short* __restrict__ mem3b, const float* __restrict__ wv,
    const float* __restrict__ bv, float* __restrict__ feat)
{
    const int b = blockIdx.x;
    const int tid = threadIdx.x;
    const int wid = tid >> 6, lane = tid & 63;
    __shared__ float ws_[512];
    __shared__ float part[4][512];
    __shared__ float red[256];
    __shared__ float us[512];
    __shared__ float W1s;
#pragma unroll
    for (int h = 0; h < 2; h++) {
        const int s = tid + h * 256;
        float w = 0.f;
#pragma unroll
        for (int z = 0; z < 4; z++)
            w += waccp[(((size_t)z * Bn + b) * TTn) + s];
        ws_[s] = w;
    }
    __syncthreads();
    float a[8] = {0.f, 0.f, 0.f, 0.f, 0.f, 0.f, 0.f, 0.f};
    const unsigned short* Xb = mem3b + (size_t)b * TTn * Hn + lane * 8;
    for (int s = wid * 128; s < wid * 128 + 128; s++) {
        const float w = ws_[s];
        const us8v xv = *(const us8v*)(Xb + (size_t)s * Hn);
#pragma unroll
        for (int j = 0; j < 8; j++) a[j] += w * bf2f(xv[j]);
    }
#pragma unroll
    for (int j = 0; j < 8; j++) part[wid][lane * 8 + j] = a[j];
    red[tid] = ws_[tid] + ws_[tid + 256];
    __syncthreads();
    for (int st = 128; st > 0; st >>= 1) {
        if (tid < st) red[tid] += red[tid + st];
        __syncthreads();
    }
    if (tid == 0) W1s = red[0];
    if (wid == 0) {
#pragma unroll
        for (int j = 0; j < 8; j++) {
            const int e = lane * 8 + j;
            us[e] = part[0][e] + part[1][e] + part[2][e] + part[3][e];
        }
    }
    __syncthreads();
    const float w1 = W1s;
#pragma unroll
    for (int q = 0; q < 2; q++) {
        int d = tid + q * 256;
        float acc = bv[d] * w1;
        const float* wr = wv + (size_t)d * 512;
        for (int e = 0; e < 512; e += 4) {
            float4 w4 = *(const float4*)(wr + e);
            acc += us[e] * w4.x + us[e+1] * w4.y + us[e+2] * w4.z + us[e+3] * w4.w;
        }
        feat[(size_t)b * Hn + d] = acc;
    }
}

// Parallel BN over batch: 8 blocks x 64 d; 4-way b-split + LDS reduce.
__global__ __launch_bounds__(256) void bna_k(const float* __restrict__ feat,
    const float* __restrict__ g, const float* __restrict__ bb,
    float* __restrict__ featn)
{
    const int d0 = blockIdx.x * 64;
    const int dl = threadIdx.x & 63, bg = threadIdx.x >> 6;
    float s = 0.f, ss = 0.f;
    for (int b = bg * 32; b < bg * 32 + 32; b++) {
        float v = feat[(size_t)b * Hn + d0 + dl];
        s += v; ss += v * v;
    }
    __shared__ float ls[4][64], lss[4][64];
    __shared__ float sc_s[64], sh_s[64];
    ls[bg][dl] = s; lss[bg][dl] = ss;
    __syncthreads();
    if (threadIdx.x < 64) {
        float st  = ls[0][dl] + ls[1][dl] + ls[2][dl] + ls[3][dl];
        float sst = lss[0][dl] + lss[1][dl] + lss[2][dl] + lss[3][dl];
        float m = st * (1.f / 128.f);
        float var = sst * (1.f / 128.f) - m * m;
        float sc = g[d0 + dl] / sqrtf(var + EPSF);
        sc_s[dl] = sc;
        sh_s[dl] = bb[d0 + dl] - m * sc;
    }
    __syncthreads();
    for (int b = bg * 32; b < bg * 32 + 32; b++)
        featn[(size_t)b * Hn + d0 + dl] =
            feat[(size_t)b * Hn + d0 + dl] * sc_s[dl] + sh_s[dl];
}

__global__ __launch_bounds__(128) void head_k(const float* __restrict__ featn,
    const float* __restrict__ wh, const float* __restrict__ bh, float* __restrict__ out)
{
    const int b = blockIdx.x;
    __shared__ float f[512];
    const int tid = threadIdx.x;
    for (int i = tid; i < 512; i += 128) f[i] = featn[(size_t)b * Hn + i];
    __syncthreads();
    if (tid < HORn) {
        float accv = bh[tid];
        const float* wr = wh + (size_t)tid * Hn;
        for (int d = 0; d < 512; d++) accv += f[d] * wr[d];
        out[(size_t)b * HORn + tid] = accv;
    }
}

__global__ void dbg_k(float* out, float v) { out[0] = v; }

// ---------------------------------------------------------------------------
extern "C" void kernel_launch(void* const* d_in, const int* in_sizes, int n_in,
                              void* d_out, int out_size, void* d_ws, size_t ws_size,
                              hipStream_t stream)
{
    (void)in_sizes; (void)n_in;
    const float* x      = (const float*)d_in[0];
    const float* conv_w = (const float*)d_in[1];
    const float* bn1_g  = (const float*)d_in[3];
    const float* bn1_b  = (const float*)d_in[4];
    const float* beta_e = (const float*)d_in[5];
    const float* bn2_g  = (const float*)d_in[6];
    const float* bn2_b  = (const float*)d_in[7];
    const float* beta2  = (const float*)d_in[8];
    const float* bn3_g  = (const float*)d_in[9];
    const float* bn3_b  = (const float*)d_in[10];
    const float* beta3  = (const float*)d_in[11];
    const float* wq     = (const float*)d_in[12];
    const float* bq     = (const float*)d_in[13];
    const float* wk     = (const float*)d_in[14];
    const float* bk     = (const float*)d_in[15];
    const float* wv     = (const float*)d_in[16];
    const float* bv     = (const float*)d_in[17];
    const float* bna_g  = (const float*)d_in[18];
    const float* bna_b  = (const float*)d_in[19];
    const float* wh     = (const float*)d_in[20];
    const float* bh     = (const float*)d_in[21];
    float* out = (float*)d_out;

    char* ws = (char*)d_ws;
    size_t off = 0;
    auto alloc = [&](size_t bytes) {
        char* p = ws + off;
        off += (bytes + 255) & ~(size_t)255;
        return p;
    };
    // Region 1: fp32 raw (tt,b,h) 134 MB; aliased by bf16 mem3 (b,tt,h) after lif1.
    float* raw          = (float*)alloc((size_t)TTn * BH * 4);
    // Region 2: spk1 + s2 (67 MB); aliased by bf16 Y (67 MB) after lif3.
    unsigned char* spk1 = (unsigned char*)alloc((size_t)TTn * BH);
    unsigned char* s2   = (unsigned char*)alloc((size_t)TTn * BH);
    unsigned short* Ph = (unsigned short*)alloc((size_t)NPim * 2);
    unsigned short* Pl = (unsigned short*)alloc((size_t)NPim * 2);
    unsigned short* Wh = (unsigned short*)alloc((size_t)NPw * 2);
    unsigned short* Wl = (unsigned short*)alloc((size_t)NPw * 2);
    float* sums   = (float*)alloc(2 * On * 4);
    float* a2     = (float*)alloc((size_t)TTn * Hn * 4);
    float* z2     = (float*)alloc((size_t)TTn * Hn * 4);
    float* a3     = (float*)alloc((size_t)TTn * Hn * 4);
    float* z3     = (float*)alloc((size_t)TTn * Hn * 4);
    float* waccp  = (float*)alloc((size_t)4 * Bn * TTn * 4);   // per-m-tile slices
    float* GTp    = (float*)alloc((size_t)8 * Hn * Hn * 4);    // split-K partials
    unsigned short* GT = (unsigned short*)alloc((size_t)Hn * Hn * 2);
    float* qb     = (float*)alloc(Hn * 4);
    float* kb     = (float*)alloc(Hn * 4);
    float* c0     = (float*)alloc(256);
    float* rowq   = (float*)alloc((size_t)Bn * TTn * 4);
    float* rowk   = (float*)alloc((size_t)Bn * TTn * 4);
    float* feat   = (float*)alloc((size_t)Bn * Hn * 4);
    float* featn  = (float*)alloc((size_t)Bn * Hn * 4);
    unsigned short* mem3b = (unsigned short*)raw;   // raw dead after lif1
    unsigned short* Y     = (unsigned short*)spk1;  // spikes dead after lif3

    if (ws_size < off) {
        hipMemsetAsync(d_out, 0, (size_t)out_size * 4, stream);
        dbg_k<<<1, 1, 0, stream>>>(out, (float)ws_size);
        return;
    }

    prep_k<<<(NPim + NPw + 255) / 256, 256, 0, stream>>>(x, conv_w, Ph, Pl, Wh, Wl, sums);
    conv_mfma_k<<<dim3(Bn, On / 128), 256, 0, stream>>>(Ph, Pl, Wh, Wl, raw, sums);
    lif1_k<<<BH / 256, 256, 0, stream>>>(raw, sums, bn1_g, bn1_b, beta_e, spk1);
    bnstep_k<<<TTn, 256, 0, stream>>>(spk1, bn2_g, bn2_b, a2, z2);
    lif2_k<<<BH / 256, 256, 0, stream>>>(spk1, a2, z2, beta2, s2);
    bnstep_k<<<TTn, 256, 0, stream>>>(s2, bn3_g, bn3_b, a3, z3);
    lif3_k<<<BH / 256, 256, 0, stream>>>(s2, a3, z3, beta3, mem3b);
    gemm_atb_k<<<dim3(4, 4, 8), 256, 0, stream>>>(wk, wq, GTp);  // split-K partials
    gtred_k<<<(Hn * Hn) / 256, 256, 0, stream>>>(GTp, GT);       // GT = G^T (bf16)
    bias_prep_k<<<17, 256, 0, stream>>>(wq, wk, bq, bk, qb, kb, c0);
    ygemm_k<<<dim3((Bn * TTn) / 128, Hn / 128), 256, 0, stream>>>(
        mem3b, GT, qb, kb, c0, Y, rowq, rowk);
    scores_k<<<dim3(TTn / 128, TTn / 128, Bn), 256, 0, stream>>>(
        Y, mem3b, rowq, rowk, waccp);
    wsumfeat_k<<<Bn, 256, 0, stream>>>(waccp, mem3b, wv, bv, feat);
    bna_k<<<Hn / 64, 256, 0, stream>>>(feat, bna_g, bna_b, featn);
    head_k<<<Bn, 128, 0, stream>>>(featn, wh, bh, out);
}

// Round 21
// 456.107 us; speedup vs baseline: 1.1810x; 1.0369x over previous
//
#include <hip/hip_runtime.h>
#include <math.h>

#define EPSF 1e-5f

static constexpr int Bn   = 128;   // batch
static constexpr int Tn   = 128;   // conv time steps
static constexpr int Cn   = 32;    // conv in channels
static constexpr int On   = 2048;  // conv out channels = H*Ts
static constexpr int Hn   = 512;
static constexpr int TTn  = 512;   // total SNN steps = T*Ts
static constexpr int HORn = 96;
static constexpr int BH   = Bn * Hn;
static constexpr float THRf = 1.0f;

__device__ __forceinline__ float bf2f(unsigned short u) {
    union { unsigned int i; float f; } v; v.i = ((unsigned int)u) << 16; return v.f;
}
__device__ __forceinline__ unsigned short f2bf(float f) {
    union { float f; unsigned int i; } v; v.f = f;
    unsigned int r = v.i + 0x7fff + ((v.i >> 16) & 1);   // RNE
    return (unsigned short)(r >> 16);
}

using bfrag  = __attribute__((ext_vector_type(8))) short;   // 8 bf16 = 4 VGPRs
using f32x4v = __attribute__((ext_vector_type(4))) float;   // MFMA C/D 16x16
using f32x16 = __attribute__((ext_vector_type(16))) float;  // MFMA C/D 32x32
using us8v   = __attribute__((ext_vector_type(8))) unsigned short;

// Async global->LDS DMA, 16 B per lane; LDS dest = uniform base + lane*16.
#define GLD16(gp, lp) __builtin_amdgcn_global_load_lds( \
    (const __attribute__((address_space(1))) void*)(gp), \
    (__attribute__((address_space(3))) void*)(lp), 16, 0, 0)

// ---------------------------------------------------------------------------
// Merged prep: im2col split-bf16 (idx < NPim), weight repack, sums zeroing.
static constexpr int NPim = Bn * Tn * 96;     // 1572864
static constexpr int NPw  = On * 96;          // 196608
__global__ __launch_bounds__(256) void prep_k(const float* __restrict__ x,
    const float* __restrict__ wconv, unsigned short* __restrict__ Ph,
    unsigned short* __restrict__ Pl, unsigned short* __restrict__ Wh,
    unsigned short* __restrict__ Wl, float* __restrict__ sums)
{
    int idx = blockIdx.x * 256 + threadIdx.x;
    if (idx < 2 * On) sums[idx] = 0.f;        // conv runs after prep; safe
    if (idx < NPim) {
        int row = idx / 96, kc = idx - row * 96;
        int k = kc >> 5, c = kc & 31;
        int t = row & 127, b = row >> 7;
        int tg = t + k - 1;
        float v = (tg >= 0 && tg < Tn) ? x[((size_t)b * Tn + tg) * Cn + c] : 0.f;
        unsigned short hi = f2bf(v);
        Ph[idx] = hi;
        Pl[idx] = f2bf(v - bf2f(hi));
    } else {
        int j = idx - NPim;
        if (j < NPw) {
            int o = j / 96, kc = j - o * 96;
            int k = kc >> 5, c = kc & 31;
            float v = wconv[(size_t)o * 96 + c * 3 + k];
            unsigned short hi = f2bf(v);
            Wh[j] = hi;
            Wl[j] = f2bf(v - bf2f(hi));
        }
    }
}

// Conv as NT MFMA GEMM (split-bf16, hh+hl+lh), fp32 out, fused BN1 stats.
__global__ __launch_bounds__(256) void conv_mfma_k(
    const unsigned short* __restrict__ Ph, const unsigned short* __restrict__ Pl,
    const unsigned short* __restrict__ Wh, const unsigned short* __restrict__ Wl,
    float* __restrict__ raw, float* __restrict__ sums)
{
    const int b  = blockIdx.x;
    const int n0 = blockIdx.y * 128;
    const int tid = threadIdx.x;
    const int lane = tid & 63;
    const int quad = lane >> 4, lr = lane & 15;
    const int wid = tid >> 6, wm = wid & 1, wn = wid >> 1;

    f32x4v acc[4][4] = {};
#pragma unroll
    for (int ks = 0; ks < 3; ks++) {
        const int col = ks * 32 + quad * 8;
        bfrag ah[4], al[4], bh[4], bl[4];
#pragma unroll
        for (int mi = 0; mi < 4; mi++) {
            size_t roff = ((size_t)b * 128 + wm * 64 + mi * 16 + lr) * 96 + col;
            ah[mi] = *(const bfrag*)(Ph + roff);
            al[mi] = *(const bfrag*)(Pl + roff);
        }
#pragma unroll
        for (int ni = 0; ni < 4; ni++) {
            size_t roff = (size_t)(n0 + wn * 64 + ni * 16 + lr) * 96 + col;
            bh[ni] = *(const bfrag*)(Wh + roff);
            bl[ni] = *(const bfrag*)(Wl + roff);
        }
#pragma unroll
        for (int mi = 0; mi < 4; mi++)
#pragma unroll
            for (int ni = 0; ni < 4; ni++) {
                acc[mi][ni] = __builtin_amdgcn_mfma_f32_16x16x32_bf16(
                    ah[mi], bh[ni], acc[mi][ni], 0, 0, 0);
                acc[mi][ni] = __builtin_amdgcn_mfma_f32_16x16x32_bf16(
                    ah[mi], bl[ni], acc[mi][ni], 0, 0, 0);
                acc[mi][ni] = __builtin_amdgcn_mfma_f32_16x16x32_bf16(
                    al[mi], bh[ni], acc[mi][ni], 0, 0, 0);
            }
    }
#pragma unroll
    for (int ni = 0; ni < 4; ni++) {
        int o = n0 + wn * 64 + ni * 16 + lr;
        int ts = o >> 9, hh = o & 511;
        float s = 0.f, ss = 0.f;
#pragma unroll
        for (int mi = 0; mi < 4; mi++)
#pragma unroll
            for (int r = 0; r < 4; r++) {
                int t = wm * 64 + mi * 16 + quad * 4 + r;
                float v = acc[mi][ni][r];
                raw[((size_t)(t * 4 + ts) * Bn + b) * Hn + hh] = v;
                s += v; ss += v * v;
            }
        s  += __shfl_xor(s, 16);  s  += __shfl_xor(s, 32);
        ss += __shfl_xor(ss, 16); ss += __shfl_xor(ss, 32);
        if (quad == 0) {
            atomicAdd(&sums[o], s);
            atomicAdd(&sums[On + o], ss);
        }
    }
}

// ---------------------------------------------------------------------------
// stage1: blocks 0..255 = lif1 (r17 config);  blocks 256..383 = split-K
// gemm_atb;  blocks 384..400 = bias_prep.  All three are mutually independent.
__global__ __launch_bounds__(256) void stage1_k(
    const float* __restrict__ raw, const float* __restrict__ sums,
    const float* __restrict__ g, const float* __restrict__ bb,
    const float* __restrict__ beta_in, unsigned char* __restrict__ spk,
    const float* __restrict__ wq, const float* __restrict__ wk,
    const float* __restrict__ bq, const float* __restrict__ bk,
    float* __restrict__ GTp, float* __restrict__ qb, float* __restrict__ kb,
    float* __restrict__ c0)
{
    __shared__ float As[8][132];
    __shared__ float Bs[8][132];
    __shared__ float red[256];
    __shared__ float red2[4][64];
    const int blk = blockIdx.x;
    const int tid = threadIdx.x;

    if (blk < 256) {
        // ---- lif1: BN1 finalize inlined, 16-deep scan ----
        const int thr = blk * 256 + tid;
        const int hh = thr & 511;
        const float beta = fminf(fmaxf(beta_in[hh], 0.f), 0.99f);
        float sc[4], sh[4];
#pragma unroll
        for (int ts = 0; ts < 4; ts++) {
            const int o = ts * Hn + hh;
            float m = sums[o] * (1.f / 16384.f);
            float v = sums[On + o] * (1.f / 16384.f) - m * m;
            float scv = g[o] / sqrtf(v + EPSF);
            sc[ts] = scv;
            sh[ts] = bb[o] - m * scv;
        }
        float mem = 0.f;
        for (int tt = 0; tt < TTn; tt += 16) {
            float cu[16];
#pragma unroll
            for (int u = 0; u < 16; u++) cu[u] = raw[(size_t)(tt + u) * BH + thr];
#pragma unroll
            for (int u = 0; u < 16; u++) {
                float cur = cu[u] * sc[u & 3] + sh[u & 3];
                float reset = mem > THRf ? 1.f : 0.f;
                mem = beta * mem + cur - reset;
                spk[(size_t)(tt + u) * BH + thr] = mem > THRf ? (unsigned char)1 : (unsigned char)0;
            }
        }
    } else if (blk < 384) {
        // ---- gemm_atb split-K partial ----
        const int i = blk - 256;
        const int m0 = (i & 3) * 128;
        const int n0 = ((i >> 2) & 3) * 128;
        const int kz = i >> 4;
        const int ir = tid >> 5, cl = (tid & 31) * 4;
        const float* Ap = wk + (size_t)ir * 512 + m0 + cl;
        const float* Bp = wq + (size_t)ir * 512 + n0 + cl;
        const int tm = tid & 15, tn = tid >> 4;
        float acc[8][8];
#pragma unroll
        for (int a = 0; a < 8; a++)
#pragma unroll
            for (int j = 0; j < 8; j++) acc[a][j] = 0.f;

        for (int i0 = kz * 64; i0 < kz * 64 + 64; i0 += 8) {
            const float4 avv = *(const float4*)(Ap + (size_t)i0 * 512);
            const float4 bvv = *(const float4*)(Bp + (size_t)i0 * 512);
            __syncthreads();
            *(float4*)&As[ir][cl] = avv;
            *(float4*)&Bs[ir][cl] = bvv;
            __syncthreads();
#pragma unroll
            for (int kk = 0; kk < 8; kk++) {
                float4 a0 = *(const float4*)&As[kk][tm * 8];
                float4 a1 = *(const float4*)&As[kk][tm * 8 + 4];
                float4 b0 = *(const float4*)&Bs[kk][tn * 8];
                float4 b1 = *(const float4*)&Bs[kk][tn * 8 + 4];
                float a_[8] = {a0.x, a0.y, a0.z, a0.w, a1.x, a1.y, a1.z, a1.w};
                float b_[8] = {b0.x, b0.y, b0.z, b0.w, b1.x, b1.y, b1.z, b1.w};
#pragma unroll
                for (int a = 0; a < 8; a++)
#pragma unroll
                    for (int j = 0; j < 8; j++) acc[a][j] += a_[a] * b_[j];
            }
        }
        float* outp = GTp + (size_t)kz * Hn * Hn;
#pragma unroll
        for (int a = 0; a < 8; a++) {
            size_t rowoff = (size_t)(m0 + tm * 8 + a) * 512 + n0 + tn * 8;
#pragma unroll
            for (int j = 0; j < 8; j++) outp[rowoff + j] = acc[a][j];
        }
    } else {
        // ---- bias_prep (17 blocks) ----
        const int bp = blk - 384;
        if (bp == 16) {
            float p = 0.f;
            for (int i = tid; i < 512; i += 256) p += bq[i] * bk[i];
            red[tid] = p;
            __syncthreads();
            for (int s = 128; s > 0; s >>= 1) {
                if (tid < s) red[tid] += red[tid + s];
                __syncthreads();
            }
            if (tid == 0) c0[0] = red[0];
            return;
        }
        const bool doq = bp < 8;
        const int d0 = (doq ? bp : bp - 8) * 64;
        const float* W    = doq ? wq : wk;
        const float* bvec = doq ? bk : bq;
        const int dl = tid & 63, ig = tid >> 6;
        float s = 0.f;
        for (int i = ig * 128; i < ig * 128 + 128; i++)
            s += W[(size_t)i * 512 + d0 + dl] * bvec[i];
        red2[ig][dl] = s;
        __syncthreads();
        if (ig == 0)
            (doq ? qb : kb)[d0 + dl] = red2[0][dl] + red2[1][dl] + red2[2][dl] + red2[3][dl];
    }
}

// ---------------------------------------------------------------------------
// stage2: blocks 0..511 = bnstep (per-step BN); blocks 512..1535 = gtred
// (reduce 8 K-slices of GTp -> bf16 GT, produced in stage1).
__global__ __launch_bounds__(256) void stage2_k(const unsigned char* __restrict__ spk,
    const float* __restrict__ g, const float* __restrict__ bb,
    float* __restrict__ av, float* __restrict__ zv,
    const float* __restrict__ GTp, unsigned short* __restrict__ GT)
{
    __shared__ uint4 part[8][32];
    const int tid = threadIdx.x;
    if (blockIdx.x < 512) {
        const int tt = blockIdx.x;
        const int b0 = tid >> 5;               // 0..7
        const int hseg = (tid & 31) * 16;      // 16 h-bytes per thread
        const unsigned char* base = spk + (size_t)tt * BH;
        uint4 a4 = make_uint4(0u, 0u, 0u, 0u);
#pragma unroll
        for (int i = 0; i < 16; i++) {
            const int b = b0 + i * 8;
            const uint4 v = *(const uint4*)(base + (size_t)b * Hn + hseg);
            a4.x += v.x; a4.y += v.y; a4.z += v.z; a4.w += v.w;
        }
        part[b0][tid & 31] = a4;
        __syncthreads();
        if (tid < 32) {
            uint4 s = part[0][tid];
#pragma unroll
            for (int i = 1; i < 8; i++) {
                uint4 p = part[i][tid];
                s.x += p.x; s.y += p.y; s.z += p.z; s.w += p.w;
            }
            unsigned int w[4] = {s.x, s.y, s.z, s.w};
#pragma unroll
            for (int q = 0; q < 16; q++) {
                int cnt = (w[q >> 2] >> ((q & 3) * 8)) & 0xff;
                int hh = tid * 16 + q;
                float p = cnt * (1.f / 128.f);
                float inv = 1.f / sqrtf(p - p * p + EPSF);
                float gi = g[hh] * inv;
                float zz = bb[hh] - p * gi;
                av[(size_t)tt * Hn + hh] = gi + zz;
                zv[(size_t)tt * Hn + hh] = zz;
            }
        }
    } else {
        int idx = (blockIdx.x - 512) * 256 + tid;   // 262144
        float s = 0.f;
#pragma unroll
        for (int z = 0; z < 8; z++) s += GTp[(size_t)z * Hn * Hn + idx];
        GT[idx] = f2bf(s);
    }
}

// Second per-step BN (standalone; nothing independent left to pair with).
__global__ __launch_bounds__(256) void bnstep_k(const unsigned char* __restrict__ spk,
    const float* __restrict__ g, const float* __restrict__ bb,
    float* __restrict__ av, float* __restrict__ zv)
{
    const int tt = blockIdx.x;
    const int tid = threadIdx.x;
    const int b0 = tid >> 5;
    const int hseg = (tid & 31) * 16;
    const unsigned char* base = spk + (size_t)tt * BH;
    uint4 a4 = make_uint4(0u, 0u, 0u, 0u);
#pragma unroll
    for (int i = 0; i < 16; i++) {
        const int b = b0 + i * 8;
        const uint4 v = *(const uint4*)(base + (size_t)b * Hn + hseg);
        a4.x += v.x; a4.y += v.y; a4.z += v.z; a4.w += v.w;
    }
    __shared__ uint4 part[8][32];
    part[b0][tid & 31] = a4;
    __syncthreads();
    if (tid < 32) {
        uint4 s = part[0][tid];
#pragma unroll
        for (int i = 1; i < 8; i++) {
            uint4 p = part[i][tid];
            s.x += p.x; s.y += p.y; s.z += p.z; s.w += p.w;
        }
        unsigned int w[4] = {s.x, s.y, s.z, s.w};
#pragma unroll
        for (int q = 0; q < 16; q++) {
            int cnt = (w[q >> 2] >> ((q & 3) * 8)) & 0xff;
            int hh = tid * 16 + q;
            float p = cnt * (1.f / 128.f);
            float inv = 1.f / sqrtf(p - p * p + EPSF);
            float gi = g[hh] * inv;
            float zz = bb[hh] - p * gi;
            av[(size_t)tt * Hn + hh] = gi + zz;
            zv[(size_t)tt * Hn + hh] = zz;
        }
    }
}

__global__ __launch_bounds__(256) void lif2_k(const unsigned char* __restrict__ sin_,
    const float* __restrict__ av, const float* __restrict__ zv,
    const float* __restrict__ beta_in, unsigned char* __restrict__ sout)
{
    const int thr = blockIdx.x * 256 + threadIdx.x;
    const int hh = thr & 511;
    const float beta = fminf(fmaxf(beta_in[hh], 0.f), 0.99f);
    float mem = 0.f;
    for (int tt = 0; tt < TTn; tt += 16) {
        float aa[16], zz[16]; unsigned char ss[16];
#pragma unroll
        for (int u = 0; u < 16; u++) {
            ss[u] = sin_[(size_t)(tt + u) * BH + thr];
            aa[u] = av[(size_t)(tt + u) * Hn + hh];
            zz[u] = zv[(size_t)(tt + u) * Hn + hh];
        }
#pragma unroll
        for (int u = 0; u < 16; u++) {
            float cur = ss[u] ? aa[u] : zz[u];
            float reset = mem > THRf ? 1.f : 0.f;
            mem = beta * mem + cur - reset;
            sout[(size_t)(tt + u) * BH + thr] = mem > THRf ? (unsigned char)1 : (unsigned char)0;
        }
    }
}

__global__ __launch_bounds__(256) void lif3_k(const unsigned char* __restrict__ sin_,
    const float* __restrict__ av, const float* __restrict__ zv,
    const float* __restrict__ beta_in, unsigned short* __restrict__ mem3b)
{
    const int thr = blockIdx.x * 256 + threadIdx.x;
    const int hh = thr & 511;
    const int b = thr >> 9;
    const float beta = fminf(fmaxf(beta_in[hh], 0.f), 0.99f);
    float mem = 0.f;
    for (int tt = 0; tt < TTn; tt += 16) {
        float aa[16], zz[16]; unsigned char ss[16];
#pragma unroll
        for (int u = 0; u < 16; u++) {
            ss[u] = sin_[(size_t)(tt + u) * BH + thr];
            aa[u] = av[(size_t)(tt + u) * Hn + hh];
            zz[u] = zv[(size_t)(tt + u) * Hn + hh];
        }
#pragma unroll
        for (int u = 0; u < 16; u++) {
            float cur = ss[u] ? aa[u] : zz[u];
            float reset = mem > THRf ? 1.f : 0.f;
            mem = beta * mem + cur - reset;
            mem3b[((size_t)b * TTn + (tt + u)) * Hn + hh] = f2bf(mem);
        }
    }
}

// ---------------------------------------------------------------------------
// m97-style MFMA NT GEMM, BK=64, 32x32x16 core, 2-D grid (r13 best config):
// Y[r,e] = sum_d mem3b[r,d] * GT[e,d].  Fused rowq/rowk on blockIdx.y==0.
__global__ __launch_bounds__(256) void ygemm_k(const unsigned short* __restrict__ A,
    const unsigned short* __restrict__ Bsrc, const float* __restrict__ qb,
    const float* __restrict__ kb, const float* __restrict__ c0,
    unsigned short* __restrict__ C, float* __restrict__ rowq,
    float* __restrict__ rowk)
{
    __shared__ unsigned short As[128 * 64];   // 16 KB
    __shared__ unsigned short Bs[128 * 64];
    const int m0 = blockIdx.x * 128;
    const int n0 = blockIdx.y * 128;
    const int tid = threadIdx.x;
    const int lane = tid & 63;
    const int l31 = lane & 31, kw = lane >> 5;
    const int wid = tid >> 6;
    const int wm = wid & 1, wn = wid >> 1;

    const int srw = lane >> 3;
    const int scc = (lane & 7) ^ (srw & 7);
    const unsigned short* gA = A    + (size_t)(m0 + wid * 32 + srw) * 512 + scc * 8;
    const unsigned short* gB = Bsrc + (size_t)(n0 + wid * 32 + srw) * 512 + scc * 8;

    const bool dorows = (blockIdx.y == 0) && (wn == 0);
    float rq_acc[2] = {0.f, 0.f};
    float rk_acc[2] = {0.f, 0.f};

    f32x16 acc[2][2] = {};
    for (int k0 = 0; k0 < 512; k0 += 64) {
        __syncthreads();
#pragma unroll
        for (int j = 0; j < 4; j++) {
            GLD16(gA + (size_t)j * 8 * 512 + k0, As + (wid * 32 + j * 8) * 64);
            GLD16(gB + (size_t)j * 8 * 512 + k0, Bs + (wid * 32 + j * 8) * 64);
        }
        __syncthreads();
#pragma unroll
        for (int kk = 0; kk < 4; kk++) {           // ksteps of 16
            const int chunk = kk * 2 + kw;
            bfrag af[2], bf_[2];
#pragma unroll
            for (int mi = 0; mi < 2; mi++) {
                const int row = wm * 64 + mi * 32 + l31;
                af[mi] = *(const bfrag*)&As[row * 64 + (chunk ^ (row & 7)) * 8];
            }
#pragma unroll
            for (int ni = 0; ni < 2; ni++) {
                const int row = wn * 64 + ni * 32 + l31;
                bf_[ni] = *(const bfrag*)&Bs[row * 64 + (chunk ^ (row & 7)) * 8];
            }
#pragma unroll
            for (int mi = 0; mi < 2; mi++)
#pragma unroll
                for (int ni = 0; ni < 2; ni++)
                    acc[mi][ni] = __builtin_amdgcn_mfma_f32_32x32x16_bf16(
                        af[mi], bf_[ni], acc[mi][ni], 0, 0, 0);
            if (dorows) {
                const int koff = k0 + kk * 16 + kw * 8;
                const float4 qv0 = *(const float4*)(qb + koff);
                const float4 qv1 = *(const float4*)(qb + koff + 4);
                const float4 kv0 = *(const float4*)(kb + koff);
                const float4 kv1 = *(const float4*)(kb + koff + 4);
                const float qv[8] = {qv0.x, qv0.y, qv0.z, qv0.w, qv1.x, qv1.y, qv1.z, qv1.w};
                const float kv[8] = {kv0.x, kv0.y, kv0.z, kv0.w, kv1.x, kv1.y, kv1.z, kv1.w};
#pragma unroll
                for (int mi = 0; mi < 2; mi++)
#pragma unroll
                    for (int j = 0; j < 8; j++) {
                        float a = bf2f((unsigned short)af[mi][j]);
                        rq_acc[mi] += a * qv[j];
                        rk_acc[mi] += a * kv[j];
                    }
            }
        }
    }
#pragma unroll
    for (int mi = 0; mi < 2; mi++)
#pragma unroll
        for (int ni = 0; ni < 2; ni++) {
            const int col = n0 + wn * 64 + ni * 32 + l31;
#pragma unroll
            for (int reg = 0; reg < 16; reg++) {
                const int row = m0 + wm * 64 + mi * 32
                              + (reg & 3) + 8 * (reg >> 2) + 4 * kw;
                C[(size_t)row * 512 + col] = f2bf(acc[mi][ni][reg]);
            }
        }
    if (dorows) {
        const float c0v = c0[0];
#pragma unroll
        for (int mi = 0; mi < 2; mi++) {
            float rq = rq_acc[mi], rk = rk_acc[mi];
            rq += __shfl_xor(rq, 32);
            rk += __shfl_xor(rk, 32);
            if (kw == 0) {
                const int row = m0 + wm * 64 + mi * 32 + l31;
                rowq[row] = rq + c0v;
                rowk[row] = rk;
            }
        }
    }
}

// m97-style MFMA scores, BK=64, 16x16x32 core, 2-D grid; atomic-free output:
// waccp[m_tile][b][s] = this block's colsum * (1/512).
__global__ __launch_bounds__(256) void scores_k(const unsigned short* __restrict__ Y,
    const unsigned short* __restrict__ Xm, const float* __restrict__ rowq,
    const float* __restrict__ rowk, float* __restrict__ waccp)
{
    __shared__ unsigned short As[128 * 64];   // 16 KB
    __shared__ unsigned short Bs[128 * 64];
    __shared__ float colsum[128];
    __shared__ float rq_s[128], rk_s[128];
    const int b  = blockIdx.z;
    const int m0 = blockIdx.x * 128;   // t tile
    const int n0 = blockIdx.y * 128;   // s tile
    const int tid = threadIdx.x;
    const int lane = tid & 63;
    const int quad = lane >> 4, lr = lane & 15;
    const int wid = tid >> 6;
    const int wm = wid & 1, wn = wid >> 1;

    if (tid < 128) {
        colsum[tid] = 0.f;
        rq_s[tid] = rowq[(size_t)b * TTn + m0 + tid];
        rk_s[tid] = rowk[(size_t)b * TTn + n0 + tid];
    }

    const int srw = lane >> 3;                       // row-within-8
    const int scc = (lane & 7) ^ (srw & 7);          // global chunk
    const unsigned short* gA = Y  + (size_t)b * TTn * Hn
        + (size_t)(m0 + wid * 32 + srw) * 512 + scc * 8;
    const unsigned short* gB = Xm + (size_t)b * TTn * Hn
        + (size_t)(n0 + wid * 32 + srw) * 512 + scc * 8;

    f32x4v acc[4][4] = {};
    for (int k0 = 0; k0 < 512; k0 += 64) {
        __syncthreads();
#pragma unroll
        for (int j = 0; j < 4; j++) {
            GLD16(gA + (size_t)j * 8 * 512 + k0, As + (wid * 32 + j * 8) * 64);
            GLD16(gB + (size_t)j * 8 * 512 + k0, Bs + (wid * 32 + j * 8) * 64);
        }
        __syncthreads();
#pragma unroll
        for (int kk = 0; kk < 2; kk++) {
            const int slot = (kk * 4 + quad) ^ (lr & 7);
            bfrag af[4], bf_[4];
#pragma unroll
            for (int mi = 0; mi < 4; mi++)
                af[mi] = *(const bfrag*)&As[(wm * 64 + mi * 16 + lr) * 64 + slot * 8];
#pragma unroll
            for (int ni = 0; ni < 4; ni++)
                bf_[ni] = *(const bfrag*)&Bs[(wn * 64 + ni * 16 + lr) * 64 + slot * 8];
#pragma unroll
            for (int mi = 0; mi < 4; mi++)
#pragma unroll
                for (int ni = 0; ni < 4; ni++)
                    acc[mi][ni] = __builtin_amdgcn_mfma_f32_16x16x32_bf16(
                        af[mi], bf_[ni], acc[mi][ni], 0, 0, 0);
        }
    }
    const float scl = 0.044194173824159216f;
#pragma unroll
    for (int ni = 0; ni < 4; ni++) {
        float s_ln = 0.f;
        float rkv = rk_s[wn * 64 + ni * 16 + lr];
#pragma unroll
        for (int mi = 0; mi < 4; mi++) {
#pragma unroll
            for (int r = 0; r < 4; r++) {
                float rqv = rq_s[wm * 64 + mi * 16 + quad * 4 + r];
                float xv = (acc[mi][ni][r] + rqv + rkv) * scl;
                s_ln += 1.f / (1.f + __expf(-xv));
            }
        }
        atomicAdd(&colsum[wn * 64 + ni * 16 + lr], s_ln);
    }
    __syncthreads();
    if (tid < 128)
        waccp[(((size_t)blockIdx.x * Bn + b) * TTn) + n0 + tid] =
            colsum[tid] * (1.f / 512.f);
}

// Fused wsum+feat: u[b,:] built in LDS from 4 waccp slices, then
// feat[b,d] = u[b,:].wv[d,:] + bv[d]*W1[b].
__global__ __launch_bounds__(256) void wsumfeat_k(const float* __restrict__ waccp,
    const unsigned short* __restrict__ mem3b, const float* __restrict__ wv,
    const float* __restrict__ bv, float* __restrict__ feat)
{
    const int b = blockIdx.x;
    const int tid = threadIdx.x;
    const int wid = tid >> 6, lane = tid & 63;
    __shared__ float ws_[512];
    __shared__ float part[4][512];
    __shared__ float red[256];
    __shared__ float us[512];
    __shared__ float W1s;
#pragma unroll
    for (int h = 0; h < 2; h++) {
        const int s = tid + h * 256;
        float w = 0.f;
#pragma unroll
        for (int z = 0; z < 4; z++)
            w += waccp[(((size_t)z * Bn + b) * TTn) + s];
        ws_[s] = w;
    }
    __syncthreads();
    float a[8] = {0.f, 0.f, 0.f, 0.f, 0.f, 0.f, 0.f, 0.f};
    const unsigned short* Xb = mem3b + (size_t)b * TTn * Hn + lane * 8;
    for (int s = wid * 128; s < wid * 128 + 128; s++) {
        const float w = ws_[s];
        const us8v xv = *(const us8v*)(Xb + (size_t)s * Hn);
#pragma unroll
        for (int j = 0; j < 8; j++) a[j] += w * bf2f(xv[j]);
    }
#pragma unroll
    for (int j = 0; j < 8; j++) part[wid][lane * 8 + j] = a[j];
    red[tid] = ws_[tid] + ws_[tid + 256];
    __syncthreads();
    for (int st = 128; st > 0; st >>= 1) {
        if (tid < st) red[tid] += red[tid + st];
        __syncthreads();
    }
    if (tid == 0) W1s = red[0];
    if (wid == 0) {
#pragma unroll
        for (int j = 0; j < 8; j++) {
            const int e = lane * 8 + j;
            us[e] = part[0][e] + part[1][e] + part[2][e] + part[3][e];
        }
    }
    __syncthreads();
    const float w1 = W1s;
#pragma unroll
    for (int q = 0; q < 2; q++) {
        int d = tid + q * 256;
        float acc = bv[d] * w1;
        const float* wr = wv + (size_t)d * 512;
        for (int e = 0; e < 512; e += 4) {
            float4 w4 = *(const float4*)(wr + e);
            acc += us[e] * w4.x + us[e+1] * w4.y + us[e+2] * w4.z + us[e+3] * w4.w;
        }
        feat[(size_t)b * Hn + d] = acc;
    }
}

// Parallel BN over batch: 8 blocks x 64 d; 4-way b-split + LDS reduce.
__global__ __launch_bounds__(256) void bna_k(const float* __restrict__ feat,
    const float* __restrict__ g, const float* __restrict__ bb,
    float* __restrict__ featn)
{
    const int d0 = blockIdx.x * 64;
    const int dl = threadIdx.x & 63, bg = threadIdx.x >> 6;
    float s = 0.f, ss = 0.f;
    for (int b = bg * 32; b < bg * 32 + 32; b++) {
        float v = feat[(size_t)b * Hn + d0 + dl];
        s += v; ss += v * v;
    }
    __shared__ float ls[4][64], lss[4][64];
    __shared__ float sc_s[64], sh_s[64];
    ls[bg][dl] = s; lss[bg][dl] = ss;
    __syncthreads();
    if (threadIdx.x < 64) {
        float st  = ls[0][dl] + ls[1][dl] + ls[2][dl] + ls[3][dl];
        float sst = lss[0][dl] + lss[1][dl] + lss[2][dl] + lss[3][dl];
        float m = st * (1.f / 128.f);
        float var = sst * (1.f / 128.f) - m * m;
        float sc = g[d0 + dl] / sqrtf(var + EPSF);
        sc_s[dl] = sc;
        sh_s[dl] = bb[d0 + dl] - m * sc;
    }
    __syncthreads();
    for (int b = bg * 32; b < bg * 32 + 32; b++)
        featn[(size_t)b * Hn + d0 + dl] =
            feat[(size_t)b * Hn + d0 + dl] * sc_s[dl] + sh_s[dl];
}

__global__ __launch_bounds__(128) void head_k(const float* __restrict__ featn,
    const float* __restrict__ wh, const float* __restrict__ bh, float* __restrict__ out)
{
    const int b = blockIdx.x;
    __shared__ float f[512];
    const int tid = threadIdx.x;
    for (int i = tid; i < 512; i += 128) f[i] = featn[(size_t)b * Hn + i];
    __syncthreads();
    if (tid < HORn) {
        float accv = bh[tid];
        const float* wr = wh + (size_t)tid * Hn;
        for (int d = 0; d < 512; d++) accv += f[d] * wr[d];
        out[(size_t)b * HORn + tid] = accv;
    }
}

__global__ void dbg_k(float* out, float v) { out[0] = v; }

// ---------------------------------------------------------------------------
extern "C" void kernel_launch(void* const* d_in, const int* in_sizes, int n_in,
                              void* d_out, int out_size, void* d_ws, size_t ws_size,
                              hipStream_t stream)
{
    (void)in_sizes; (void)n_in;
    const float* x      = (const float*)d_in[0];
    const float* conv_w = (const float*)d_in[1];
    const float* bn1_g  = (const float*)d_in[3];
    const float* bn1_b  = (const float*)d_in[4];
    const float* beta_e = (const float*)d_in[5];
    const float* bn2_g  = (const float*)d_in[6];
    const float* bn2_b  = (const float*)d_in[7];
    const float* beta2  = (const float*)d_in[8];
    const float* bn3_g  = (const float*)d_in[9];
    const float* bn3_b  = (const float*)d_in[10];
    const float* beta3  = (const float*)d_in[11];
    const float* wq     = (const float*)d_in[12];
    const float* bq     = (const float*)d_in[13];
    const float* wk     = (const float*)d_in[14];
    const float* bk     = (const float*)d_in[15];
    const float* wv     = (const float*)d_in[16];
    const float* bv     = (const float*)d_in[17];
    const float* bna_g  = (const float*)d_in[18];
    const float* bna_b  = (const float*)d_in[19];
    const float* wh     = (const float*)d_in[20];
    const float* bh     = (const float*)d_in[21];
    float* out = (float*)d_out;

    char* ws = (char*)d_ws;
    size_t off = 0;
    auto alloc = [&](size_t bytes) {
        char* p = ws + off;
        off += (bytes + 255) & ~(size_t)255;
        return p;
    };
    // Region 1: fp32 raw (tt,b,h) 134 MB; aliased by bf16 mem3 (b,tt,h) after lif1.
    float* raw          = (float*)alloc((size_t)TTn * BH * 4);
    // Region 2: spk1 + s2 (67 MB); aliased by bf16 Y (67 MB) after lif3.
    unsigned char* spk1 = (unsigned char*)alloc((size_t)TTn * BH);
    unsigned char* s2   = (unsigned char*)alloc((size_t)TTn * BH);
    unsigned short* Ph = (unsigned short*)alloc((size_t)NPim * 2);
    unsigned short* Pl = (unsigned short*)alloc((size_t)NPim * 2);
    unsigned short* Wh = (unsigned short*)alloc((size_t)NPw * 2);
    unsigned short* Wl = (unsigned short*)alloc((size_t)NPw * 2);
    float* sums   = (float*)alloc(2 * On * 4);
    float* a2     = (float*)alloc((size_t)TTn * Hn * 4);
    float* z2     = (float*)alloc((size_t)TTn * Hn * 4);
    float* a3     = (float*)alloc((size_t)TTn * Hn * 4);
    float* z3     = (float*)alloc((size_t)TTn * Hn * 4);
    float* waccp  = (float*)alloc((size_t)4 * Bn * TTn * 4);   // per-m-tile slices
    float* GTp    = (float*)alloc((size_t)8 * Hn * Hn * 4);    // split-K partials
    unsigned short* GT = (unsigned short*)alloc((size_t)Hn * Hn * 2);
    float* qb     = (float*)alloc(Hn * 4);
    float* kb     = (float*)alloc(Hn * 4);
    float* c0     = (float*)alloc(256);
    float* rowq   = (float*)alloc((size_t)Bn * TTn * 4);
    float* rowk   = (float*)alloc((size_t)Bn * TTn * 4);
    float* feat   = (float*)alloc((size_t)Bn * Hn * 4);
    float* featn  = (float*)alloc((size_t)Bn * Hn * 4);
    unsigned short* mem3b = (unsigned short*)raw;   // raw dead after lif1
    unsigned short* Y     = (unsigned short*)spk1;  // spikes dead after lif3

    if (ws_size < off) {
        hipMemsetAsync(d_out, 0, (size_t)out_size * 4, stream);
        dbg_k<<<1, 1, 0, stream>>>(out, (float)ws_size);
        return;
    }

    prep_k<<<(NPim + NPw + 255) / 256, 256, 0, stream>>>(x, conv_w, Ph, Pl, Wh, Wl, sums);
    conv_mfma_k<<<dim3(Bn, On / 128), 256, 0, stream>>>(Ph, Pl, Wh, Wl, raw, sums);
    // stage1: lif1 || gemm_atb split-K || bias_prep  (401 blocks)
    stage1_k<<<256 + 128 + 17, 256, 0, stream>>>(raw, sums, bn1_g, bn1_b, beta_e,
        spk1, wq, wk, bq, bk, GTp, qb, kb, c0);
    // stage2: bnstep2 || gtred  (512 + 1024 blocks)
    stage2_k<<<512 + 1024, 256, 0, stream>>>(spk1, bn2_g, bn2_b, a2, z2, GTp, GT);
    lif2_k<<<BH / 256, 256, 0, stream>>>(spk1, a2, z2, beta2, s2);
    bnstep_k<<<TTn, 256, 0, stream>>>(s2, bn3_g, bn3_b, a3, z3);
    lif3_k<<<BH / 256, 256, 0, stream>>>(s2, a3, z3, beta3, mem3b);
    ygemm_k<<<dim3((Bn * TTn) / 128, Hn / 128), 256, 0, stream>>>(
        mem3b, GT, qb, kb, c0, Y, rowq, rowk);
    scores_k<<<dim3(TTn / 128, TTn / 128, Bn), 256, 0, stream>>>(
        Y, mem3b, rowq, rowk, waccp);
    wsumfeat_k<<<Bn, 256, 0, stream>>>(waccp, mem3b, wv, bv, feat);
    bna_k<<<Hn / 64, 256, 0, stream>>>(feat, bna_g, bna_b, featn);
    head_k<<<Bn, 128, 0, stream>>>(featn, wh, bh, out);
}